// Round 14
// baseline (111.235 us; speedup 1.0000x reference)
//
#include <hip/hip_runtime.h>

// EntityAttention — round 14: back half = pnorm (materialize normalized P
// once) + pure dense GEMM out = P @ VWt^T (no in-kernel A-build, no LDS).
// NB=8 SL=512 NH=512 EN=16 NE=64 HEADS=2 DH=256. Selection masks all-True.

#define NB 8
#define SL 512
#define NH 512
#define EN 16
#define NE 64
#define HEADS 2
#define DH 256
#define NSLOT (NB * EN)
#define SCALE 0.0625f

typedef __attribute__((ext_vector_type(8))) short short8;
typedef __attribute__((ext_vector_type(4))) short short4v;
typedef __attribute__((ext_vector_type(4))) float f32x4;

#define MFMA16(a, b, c) __builtin_amdgcn_mfma_f32_16x16x32_bf16(a, b, c, 0, 0, 0)

__device__ __forceinline__ short f2b(float f) {
    unsigned u = __builtin_bit_cast(unsigned, f);
    u += 0x7fffu + ((u >> 16) & 1u);
    return (short)(u >> 16);
}
__device__ __forceinline__ float b2f(short s) {
    return __builtin_bit_cast(float, ((unsigned)(unsigned short)s) << 16);
}
__device__ __forceinline__ int swz8(int hw, int chunk) {
    return (hw & 7) * chunk + (hw >> 3);
}

// ---- tiny GEMM helpers -----------------------------------------------------
__device__ __forceinline__ void ldg4(short8 (&d)[4], const short* p, int k, int stride) {
#pragma unroll
    for (int j = 0; j < 4; ++j) d[j] = *(const short8*)(p + (size_t)j * 16 * stride + k);
}
__device__ __forceinline__ void ldg2(short8 (&d)[2], const short* p, int k, int stride) {
#pragma unroll
    for (int j = 0; j < 2; ++j) d[j] = *(const short8*)(p + (size_t)j * 16 * stride + k);
}
__device__ __forceinline__ void mm44(f32x4 (&acc)[4][4], const short8 (&a)[4], const short8 (&bb)[4]) {
#pragma unroll
    for (int i = 0; i < 4; ++i)
#pragma unroll
        for (int j = 0; j < 4; ++j) acc[i][j] = MFMA16(a[i], bb[j], acc[i][j]);
}
__device__ __forceinline__ void mm42(f32x4 (&acc)[4][2], const short8 (&a)[4], const short8 (&bb)[2]) {
#pragma unroll
    for (int i = 0; i < 4; ++i)
#pragma unroll
        for (int j = 0; j < 2; ++j) acc[i][j] = MFMA16(a[i], bb[j], acc[i][j]);
}

// ---- ws byte offsets -------------------------------------------------------
#define WS_TOKS 0u
#define WS_K (4u << 20)
#define WS_V (8u << 20)
#define WS_S (20u << 20)   /* expS, 1 MB */
#define WS_WK (22u << 20)
#define WS_WV (WS_WK + (512u << 10))
#define WS_WO (WS_WV + (512u << 10))
#define WS_WQ (WS_WO + (512u << 10))
#define WS_EV (WS_WQ + (512u << 10))
#define WS_Q (WS_EV + (64u << 10))
#define WS_FLAG (WS_Q + (64u << 10))
#define WS_VW (24u << 20)  /* 8 MB */
#define WS_P (40u << 20)   /* 16.8 MB */

// chunk counts (f32x4 units) for prep
#define CH_TOKS (NB * SL * NH / 4)
#define CH_W (NH * NH / 4)
#define CH_EV (NE * NH / 4)
#define CH_TOTAL (CH_TOKS + 4 * CH_W + CH_EV)

// ---------------------------------------------------------------------------
__global__ void prep_kernel(const float* __restrict__ toks, const float* __restrict__ Wk,
                            const float* __restrict__ Wv, const float* __restrict__ Wo,
                            const float* __restrict__ Wq, const float* __restrict__ ev,
                            const unsigned char* __restrict__ ents,
                            short* __restrict__ toks_bf, short* __restrict__ Wk_bf,
                            short* __restrict__ Wv_bf, short* __restrict__ Wo_bf,
                            short* __restrict__ Wq_bf, short* __restrict__ ev_bf,
                            int* __restrict__ flag) {
    __shared__ int red[256];
    int idx = blockIdx.x * 256 + threadIdx.x;
    if (idx < CH_TOTAL) {
        const float* src;
        short* dst;
        int off = idx;
        if (idx < CH_TOKS) { src = toks; dst = toks_bf; }
        else if (idx < CH_TOKS + CH_W) { src = Wk; dst = Wk_bf; off -= CH_TOKS; }
        else if (idx < CH_TOKS + 2 * CH_W) { src = Wv; dst = Wv_bf; off -= CH_TOKS + CH_W; }
        else if (idx < CH_TOKS + 3 * CH_W) { src = Wo; dst = Wo_bf; off -= CH_TOKS + 2 * CH_W; }
        else if (idx < CH_TOKS + 4 * CH_W) { src = Wq; dst = Wq_bf; off -= CH_TOKS + 3 * CH_W; }
        else { src = ev; dst = ev_bf; off -= CH_TOKS + 4 * CH_W; }
        f32x4 v = ((const f32x4*)src)[off];
        short4v o;
#pragma unroll
        for (int j = 0; j < 4; ++j) o[j] = f2b(v[j]);
        ((short4v*)dst)[off] = o;
    }
    if (blockIdx.x == gridDim.x - 1) {
        int tid = threadIdx.x;
        int cnt = 0;
        for (int j = 0; j < 16; ++j) {
            int off = tid * 16 + j;
            if ((off & 3) != 0 && ents[off] != 0) cnt++;
        }
        red[tid] = cnt;
        __syncthreads();
        for (int s = 128; s > 0; s >>= 1) {
            if (tid < s) red[tid] += red[tid + s];
            __syncthreads();
        }
        if (tid == 0) flag[0] = (red[0] == 0) ? 1 : 0;
    }
}

// ---------------------------------------------------------------------------
// proj: K/V row-major + q. 128x128 tiles, 64x64/wave, 2-deep pipeline.
__global__ void __launch_bounds__(256, 2)
proj_kernel(const short* __restrict__ toks_bf,
            const short* __restrict__ Wk_bf,
            const short* __restrict__ Wv_bf,
            const short* __restrict__ ev_bf,
            const short* __restrict__ Wq_bf,
            const float* __restrict__ bk, const float* __restrict__ bv,
            const float* __restrict__ bq,
            short* __restrict__ K_bf, short* __restrict__ V_bf,
            short* __restrict__ q_bf) {
    int t = blockIdx.x;
    int tid = threadIdx.x, lane = tid & 63, wid = tid >> 6;
    int l15 = lane & 15;
    int kb = (lane >> 4) * 8;
    int crow = (lane >> 4) * 4;

    if (t < 256) {
        int l = swz8(t, 32);
        int b = l >> 5, kind = (l >> 4) & 1, mt = (l >> 2) & 3, nt = l & 3;
        int m0 = mt * 128 + (wid >> 1) * 64;
        int n0 = nt * 128 + (wid & 1) * 64;
        const short* A = toks_bf + ((size_t)b * SL + m0 + l15) * NH + kb;
        const short* B = (kind ? Wv_bf : Wk_bf) + (size_t)(n0 + l15) * NH + kb;
        const float* bias = kind ? bv : bk;
        short* dst = kind ? V_bf : K_bf;

        f32x4 acc[4][4];
#pragma unroll
        for (int i = 0; i < 4; ++i)
#pragma unroll
            for (int j = 0; j < 4; ++j) acc[i][j] = (f32x4)0.f;

        short8 a0[4], b0[4], a1[4], b1[4];
        ldg4(a0, A, 0, NH);
        ldg4(b0, B, 0, NH);
#pragma unroll
        for (int p = 0; p < 8; ++p) {
            int k1 = p * 64 + 32;
            ldg4(a1, A, k1, NH);
            ldg4(b1, B, k1, NH);
            mm44(acc, a0, b0);
            if (p < 7) {
                ldg4(a0, A, k1 + 32, NH);
                ldg4(b0, B, k1 + 32, NH);
            }
            mm44(acc, a1, b1);
        }

#pragma unroll
        for (int i = 0; i < 4; ++i) {
#pragma unroll
            for (int j = 0; j < 4; ++j) {
                int col = n0 + j * 16 + l15;
                float bval = bias[col];
                int row0 = m0 + i * 16 + crow;
#pragma unroll
                for (int r = 0; r < 4; ++r)
                    dst[((size_t)b * SL + row0 + r) * NH + col] = f2b(acc[i][j][r] + bval);
            }
        }
    } else {
        int tq = t - 256;
        int n0 = tq * 128 + wid * 32;
        const short* A = ev_bf + (size_t)l15 * NH + kb;
        const short* B = Wq_bf + (size_t)(n0 + l15) * NH + kb;

        f32x4 acc[4][2];
#pragma unroll
        for (int i = 0; i < 4; ++i)
#pragma unroll
            for (int j = 0; j < 2; ++j) acc[i][j] = (f32x4)0.f;

        for (int k = 0; k < NH; k += 32) {
            short8 a[4], bb[2];
#pragma unroll
            for (int i = 0; i < 4; ++i) a[i] = *(const short8*)(A + (size_t)i * 16 * NH + k);
#pragma unroll
            for (int j = 0; j < 2; ++j) bb[j] = *(const short8*)(B + (size_t)j * 16 * NH + k);
            mm42(acc, a, bb);
        }

#pragma unroll
        for (int i = 0; i < 4; ++i)
#pragma unroll
            for (int j = 0; j < 2; ++j) {
                int col = n0 + j * 16 + l15;
                float bval = bq[col];
#pragma unroll
                for (int r = 0; r < 4; ++r)
                    q_bf[(size_t)(i * 16 + crow + r) * NH + col] = f2b((acc[i][j][r] + bval) * SCALE);
            }
    }
}

// ---------------------------------------------------------------------------
// scores: S_bf[b][h][e][s] = EXP(q_scaled[e] . K[b][s]) bf16. grid 64.
__global__ void __launch_bounds__(256, 2)
scores_mfma(const short* __restrict__ q_bf,
            const short* __restrict__ K_bf,
            short* __restrict__ S_bf) {
    int l = swz8(blockIdx.x, 8);
    int b = l >> 3, h = (l >> 2) & 1, st = l & 3;
    int tid = threadIdx.x, lane = tid & 63, wid = tid >> 6;
    int l15 = lane & 15;
    int n0 = st * 128 + wid * 32;
    int kb = (lane >> 4) * 8;

    f32x4 acc[4][2];
#pragma unroll
    for (int i = 0; i < 4; ++i)
#pragma unroll
        for (int j = 0; j < 2; ++j) acc[i][j] = (f32x4)0.f;

    const short* Aq = q_bf + (size_t)l15 * NH + h * DH + kb;
    const short* Bk = K_bf + ((size_t)b * SL + n0 + l15) * NH + h * DH + kb;

    short8 a0[4], a1[4];
    short8 b0[2], b1[2];
    ldg4(a0, Aq, 0, NH);
    ldg2(b0, Bk, 0, NH);
#pragma unroll
    for (int p = 0; p < 4; ++p) {
        int k1 = p * 64 + 32;
        ldg4(a1, Aq, k1, NH);
        ldg2(b1, Bk, k1, NH);
        mm42(acc, a0, b0);
        if (p < 3) {
            ldg4(a0, Aq, k1 + 32, NH);
            ldg2(b0, Bk, k1 + 32, NH);
        }
        mm42(acc, a1, b1);
    }

    int crow = (lane >> 4) * 4;
#pragma unroll
    for (int i = 0; i < 4; ++i)
#pragma unroll
        for (int j = 0; j < 2; ++j) {
            int col = n0 + j * 16 + l15;
#pragma unroll
            for (int r = 0; r < 4; ++r) {
                int row = i * 16 + crow + r;
                S_bf[(((size_t)(b * HEADS + h)) * NE + row) * SL + col] = f2b(__expf(acc[i][j][r]));
            }
        }
}

// ---------------------------------------------------------------------------
// vwt: VWt[b][h][o][s] = sum_d Wo[o][h*DH+d] * V[b][s][h*DH+d], bf16. grid 256.
__global__ void __launch_bounds__(256, 2)
vwt_kernel(const short* __restrict__ V_bf,
           const short* __restrict__ Wo_bf,
           short* __restrict__ VWt) {
    int l = swz8(blockIdx.x, 32);
    int bh = l >> 4, mt = (l >> 2) & 3, nt = l & 3;
    int b = bh >> 1, h = bh & 1;
    int tid = threadIdx.x, lane = tid & 63, wid = tid >> 6;
    int l15 = lane & 15;
    int kb = (lane >> 4) * 8;
    int crow = (lane >> 4) * 4;
    int m0 = mt * 128 + (wid >> 1) * 64;
    int n0 = nt * 128 + (wid & 1) * 64;

    const short* A = Wo_bf + (size_t)(m0 + l15) * NH + h * DH + kb;
    const short* B = V_bf + ((size_t)b * SL + n0 + l15) * NH + h * DH + kb;

    f32x4 acc[4][4];
#pragma unroll
    for (int i = 0; i < 4; ++i)
#pragma unroll
        for (int j = 0; j < 4; ++j) acc[i][j] = (f32x4)0.f;

    short8 a0[4], b0[4], a1[4], b1[4];
    ldg4(a0, A, 0, NH);
    ldg4(b0, B, 0, NH);
#pragma unroll
    for (int p = 0; p < 4; ++p) {
        int k1 = p * 64 + 32;
        ldg4(a1, A, k1, NH);
        ldg4(b1, B, k1, NH);
        mm44(acc, a0, b0);
        if (p < 3) {
            ldg4(a0, A, k1 + 32, NH);
            ldg4(b0, B, k1 + 32, NH);
        }
        mm44(acc, a1, b1);
    }

    short* dst = VWt + (size_t)bh * NH * SL;
#pragma unroll
    for (int i = 0; i < 4; ++i)
#pragma unroll
        for (int j = 0; j < 4; ++j) {
            int col = n0 + j * 16 + l15;
            int row0 = m0 + i * 16 + crow;
#pragma unroll
            for (int r = 0; r < 4; ++r)
                dst[(size_t)(row0 + r) * SL + col] = f2b(acc[i][j][r]);
        }
}

// ---------------------------------------------------------------------------
// pnorm: P[(b*16+ent)*64 + e][h*512+s] = mask[b,ent,s] ? expS[b,h,e,s]*inv : 0
// where inv = 1/sum_s(mask*expS). Block = (b, ent, eh): 32 e-rows x 2 heads.
__global__ void __launch_bounds__(256, 4)
pnorm_kernel(const short* __restrict__ S_bf,
             const void* __restrict__ ents,
             const int* __restrict__ flag,
             short* __restrict__ P) {
    int l = swz8(blockIdx.x, 32); // b*32 + ent*2 + eh
    int b = l >> 5, ent = (l >> 1) & 15, eh = l & 1;
    int tid = threadIdx.x, lane = tid & 63, wid = tid >> 6;

    // mask bits for s = lane*8 + j
    unsigned att8 = 0;
    {
        size_t mbase = ((size_t)b * EN + ent) * SL + lane * 8;
        if (flag[0]) {
            const int* p = (const int*)ents;
#pragma unroll
            for (int j = 0; j < 8; ++j)
                if (p[mbase + j]) att8 |= 1u << j;
        } else {
            const unsigned char* p = (const unsigned char*)ents;
#pragma unroll
            for (int j = 0; j < 8; ++j)
                if (p[mbase + j]) att8 |= 1u << j;
        }
    }

    for (int it = 0; it < 8; ++it) {
        int e = eh * 32 + wid * 8 + it;
        const short* s0p = S_bf + (((size_t)(b * HEADS + 0)) * NE + e) * SL + lane * 8;
        const short* s1p = S_bf + (((size_t)(b * HEADS + 1)) * NE + e) * SL + lane * 8;
        short8 v0 = *(const short8*)s0p;
        short8 v1 = *(const short8*)s1p;
        float f0[8], f1[8], sum0 = 0.f, sum1 = 0.f;
#pragma unroll
        for (int j = 0; j < 8; ++j) {
            f0[j] = (att8 >> j & 1) ? b2f(v0[j]) : 0.f;
            f1[j] = (att8 >> j & 1) ? b2f(v1[j]) : 0.f;
            sum0 += f0[j];
            sum1 += f1[j];
        }
#pragma unroll
        for (int off = 32; off; off >>= 1) {
            sum0 += __shfl_xor(sum0, off);
            sum1 += __shfl_xor(sum1, off);
        }
        float iv0 = 1.f / sum0, iv1 = 1.f / sum1;
        short8 o0, o1;
#pragma unroll
        for (int j = 0; j < 8; ++j) {
            o0[j] = f2b(f0[j] * iv0);
            o1[j] = f2b(f1[j] * iv1);
        }
        short* prow = P + ((size_t)(b * EN + ent) * NE + e) * 1024;
        *(short8*)(prow + lane * 8) = o0;
        *(short8*)(prow + 512 + lane * 8) = o1;
    }
}

// ---------------------------------------------------------------------------
// outgemm: out = P @ VWt^T + bo. M=8192 (per-batch 1024), N=512, K=1024.
// 128x128 tiles, 64x64/wave, direct-global 2-deep pipeline, no LDS.
__global__ void __launch_bounds__(256, 2)
outgemm(const short* __restrict__ P,
        const short* __restrict__ VWt,
        const float* __restrict__ bo,
        float* __restrict__ out) {
    int l = swz8(blockIdx.x, 32); // b*32 + mt*4 + nt
    int b = l >> 5, mt = (l >> 2) & 7, nt = l & 3;
    int tid = threadIdx.x, lane = tid & 63, wid = tid >> 6;
    int l15 = lane & 15;
    int kb = (lane >> 4) * 8;
    int crow = (lane >> 4) * 4;
    int wm = wid >> 1, wn = wid & 1;

    const short* A = P + ((size_t)b * 1024 + mt * 128 + wm * 64 + l15) * 1024 + kb;
    const short* Bw0 = VWt + ((size_t)(b * HEADS + 0) * NH + nt * 128 + wn * 64 + l15) * SL + kb;
    const short* Bw1 = Bw0 + (size_t)NH * SL;

    f32x4 acc[4][4];
#pragma unroll
    for (int i = 0; i < 4; ++i)
#pragma unroll
        for (int j = 0; j < 4; ++j) acc[i][j] = (f32x4)0.f;

    short8 a0[4], b0[4], a1[4], b1[4];
    ldg4(a0, A, 0, 1024);
    ldg4(b0, Bw0, 0, SL);
#pragma unroll
    for (int p = 0; p < 16; ++p) {
        int k1 = p * 64 + 32;
        ldg4(a1, A, k1, 1024);
        ldg4(b1, (k1 < 512) ? Bw0 : Bw1, k1 & 511, SL);
        mm44(acc, a0, b0);
        if (p < 15) {
            int k2 = k1 + 32;
            ldg4(a0, A, k2, 1024);
            ldg4(b0, (k2 < 512) ? Bw0 : Bw1, k2 & 511, SL);
        }
        mm44(acc, a1, b1);
    }

    int gr0 = b * 1024 + mt * 128 + wm * 64;
#pragma unroll
    for (int i = 0; i < 4; ++i)
#pragma unroll
        for (int j = 0; j < 4; ++j) {
            int col = nt * 128 + wn * 64 + j * 16 + l15;
            float bval = bo[col];
#pragma unroll
            for (int r = 0; r < 4; ++r) {
                int row = gr0 + i * 16 + crow + r;
                out[(size_t)row * NH + col] = acc[i][j][r] + bval;
            }
        }
}

// ---------------------------------------------------------------------------
extern "C" void kernel_launch(void* const* d_in, const int* in_sizes, int n_in,
                              void* d_out, int out_size, void* d_ws, size_t ws_size,
                              hipStream_t stream) {
    const float* toks = (const float*)d_in[0];
    const void* ents = d_in[1];
    const float* evs = (const float*)d_in[2];
    const float* Wq = (const float*)d_in[6];
    const float* Wk = (const float*)d_in[7];
    const float* Wv = (const float*)d_in[8];
    const float* bq = (const float*)d_in[9];
    const float* bk = (const float*)d_in[10];
    const float* bv = (const float*)d_in[11];
    const float* Wo = (const float*)d_in[12];
    const float* bo = (const float*)d_in[13];

    char* ws = (char*)d_ws;
    short* toks_bf = (short*)(ws + WS_TOKS);
    short* K_bf = (short*)(ws + WS_K);
    short* V_bf = (short*)(ws + WS_V);
    short* S_bf = (short*)(ws + WS_S);
    short* Wk_bf = (short*)(ws + WS_WK);
    short* Wv_bf = (short*)(ws + WS_WV);
    short* Wo_bf = (short*)(ws + WS_WO);
    short* Wq_bf = (short*)(ws + WS_WQ);
    short* ev_bf = (short*)(ws + WS_EV);
    short* q_bf = (short*)(ws + WS_Q);
    int* flag = (int*)(ws + WS_FLAG);
    short* VWt = (short*)(ws + WS_VW);
    short* P = (short*)(ws + WS_P);

    prep_kernel<<<CH_TOTAL / 256 + 1, 256, 0, stream>>>(
        toks, Wk, Wv, Wo, Wq, evs, (const unsigned char*)ents,
        toks_bf, Wk_bf, Wv_bf, Wo_bf, Wq_bf, ev_bf, flag);
    proj_kernel<<<260, 256, 0, stream>>>(toks_bf, Wk_bf, Wv_bf, ev_bf, Wq_bf,
                                         bk, bv, bq, K_bf, V_bf, q_bf);
    scores_mfma<<<64, 256, 0, stream>>>(q_bf, K_bf, S_bf);
    vwt_kernel<<<256, 256, 0, stream>>>(V_bf, Wo_bf, VWt);
    pnorm_kernel<<<256, 256, 0, stream>>>(S_bf, ents, flag, P);
    outgemm<<<256, 256, 0, stream>>>(P, VWt, bo, (float*)d_out);
}

// Round 16
// 72.816 us; speedup vs baseline: 1.5276x; 1.5276x over previous
//
#include <hip/hip_runtime.h>

// EntityAttention — round 16: R15 with the m97_core chunk-stride bug fixed
// (aCs/bCs were 256 rows instead of 32 — chunks 1-3 staged garbage).
// m97-style GEMM core (global_load_lds staging, swizzled LDS, ds_read_b128)
// for proj/vwt/outgemm. prep/scores/pnorm unchanged.
// NB=8 SL=512 NH=512 EN=16 NE=64 HEADS=2 DH=256.

#define NB 8
#define SL 512
#define NH 512
#define EN 16
#define NE 64
#define HEADS 2
#define DH 256
#define SCALE 0.0625f

typedef __attribute__((ext_vector_type(8))) short short8;
typedef __attribute__((ext_vector_type(4))) short short4v;
typedef __attribute__((ext_vector_type(4))) float f32x4;

#define MFMA16(a, b, c) __builtin_amdgcn_mfma_f32_16x16x32_bf16(a, b, c, 0, 0, 0)

__device__ __forceinline__ short f2b(float f) {
    unsigned u = __builtin_bit_cast(unsigned, f);
    u += 0x7fffu + ((u >> 16) & 1u);
    return (short)(u >> 16);
}
__device__ __forceinline__ float b2f(short s) {
    return __builtin_bit_cast(float, ((unsigned)(unsigned short)s) << 16);
}
__device__ __forceinline__ int swz8(int hw, int chunk) {
    return (hw & 7) * chunk + (hw >> 3);
}

// async global->LDS, 16B per lane; HW writes lane l at ldsbase + l*16.
__device__ __forceinline__ void gload16(const short* g, short* l) {
    __builtin_amdgcn_global_load_lds(
        (const __attribute__((address_space(1))) unsigned int*)g,
        (__attribute__((address_space(3))) unsigned int*)l, 16, 0, 0);
}

__device__ __forceinline__ void ldg4(short8 (&d)[4], const short* p, int k, int stride) {
#pragma unroll
    for (int j = 0; j < 4; ++j) d[j] = *(const short8*)(p + (size_t)j * 16 * stride + k);
}
__device__ __forceinline__ void ldg2(short8 (&d)[2], const short* p, int k, int stride) {
#pragma unroll
    for (int j = 0; j < 2; ++j) d[j] = *(const short8*)(p + (size_t)j * 16 * stride + k);
}
__device__ __forceinline__ void mm42(f32x4 (&acc)[4][2], const short8 (&a)[4], const short8 (&bb)[2]) {
#pragma unroll
    for (int i = 0; i < 4; ++i)
#pragma unroll
        for (int j = 0; j < 2; ++j) acc[i][j] = MFMA16(a[i], bb[j], acc[i][j]);
}

// ---- ws byte offsets -------------------------------------------------------
#define WS_TOKS 0u
#define WS_K (4u << 20)
#define WS_V (8u << 20)
#define WS_S (20u << 20)
#define WS_WK (22u << 20)
#define WS_WV (WS_WK + (512u << 10))
#define WS_WO (WS_WV + (512u << 10))
#define WS_WQ (WS_WO + (512u << 10))
#define WS_EV (WS_WQ + (512u << 10))
#define WS_Q (WS_EV + (64u << 10))
#define WS_FLAG (WS_Q + (64u << 10))
#define WS_VW (24u << 20)  /* VWt2[b][o][h*512+s]: 8 MB */
#define WS_P (40u << 20)   /* P[slot][e][1024]: 16.8 MB */

#define CH_TOKS (NB * SL * NH / 4)
#define CH_W (NH * NH / 4)
#define CH_EV (NE * NH / 4)
#define CH_TOTAL (CH_TOKS + 4 * CH_W + CH_EV)

// ---------------------------------------------------------------------------
__global__ void prep_kernel(const float* __restrict__ toks, const float* __restrict__ Wk,
                            const float* __restrict__ Wv, const float* __restrict__ Wo,
                            const float* __restrict__ Wq, const float* __restrict__ ev,
                            const unsigned char* __restrict__ ents,
                            short* __restrict__ toks_bf, short* __restrict__ Wk_bf,
                            short* __restrict__ Wv_bf, short* __restrict__ Wo_bf,
                            short* __restrict__ Wq_bf, short* __restrict__ ev_bf,
                            int* __restrict__ flag) {
    __shared__ int red[256];
    int idx = blockIdx.x * 256 + threadIdx.x;
    if (idx < CH_TOTAL) {
        const float* src;
        short* dst;
        int off = idx;
        if (idx < CH_TOKS) { src = toks; dst = toks_bf; }
        else if (idx < CH_TOKS + CH_W) { src = Wk; dst = Wk_bf; off -= CH_TOKS; }
        else if (idx < CH_TOKS + 2 * CH_W) { src = Wv; dst = Wv_bf; off -= CH_TOKS + CH_W; }
        else if (idx < CH_TOKS + 3 * CH_W) { src = Wo; dst = Wo_bf; off -= CH_TOKS + 2 * CH_W; }
        else if (idx < CH_TOKS + 4 * CH_W) { src = Wq; dst = Wq_bf; off -= CH_TOKS + 3 * CH_W; }
        else { src = ev; dst = ev_bf; off -= CH_TOKS + 4 * CH_W; }
        f32x4 v = ((const f32x4*)src)[off];
        short4v o;
#pragma unroll
        for (int j = 0; j < 4; ++j) o[j] = f2b(v[j]);
        ((short4v*)dst)[off] = o;
    }
    if (blockIdx.x == gridDim.x - 1) {
        int tid = threadIdx.x;
        int cnt = 0;
        for (int j = 0; j < 16; ++j) {
            int off = tid * 16 + j;
            if ((off & 3) != 0 && ents[off] != 0) cnt++;
        }
        red[tid] = cnt;
        __syncthreads();
        for (int s = 128; s > 0; s >>= 1) {
            if (tid < s) red[tid] += red[tid + s];
            __syncthreads();
        }
        if (tid == 0) flag[0] = (red[0] == 0) ? 1 : 0;
    }
}

// ---------------------------------------------------------------------------
// m97-style core: one 128x64 C-tile, 4 waves (64x32 each), BK=64.
// LDS linear [row][64 elem]; content column-swizzled: LDS[row] byte x holds
// A[row] byte x ^ ((row&7)<<4) -> conflict-free ds_read_b128.
__device__ __forceinline__ void m97_core(
    const short* __restrict__ Ag, int lda,
    const short* __restrict__ Bg, int ldb, int K,
    short* Alds, short* Blds, int wid, int lane, f32x4 (&acc)[4][2]) {
    int wm = wid >> 1, wn = wid & 1;
    int l15 = lane & 15;
    int rl = lane >> 3;             // 0..7: row within this wave's 8-row chunk
    int xb = (lane & 7) << 4;       // byte 0..112 within the 128B row
    int kx = (xb ^ (rl << 4)) >> 1; // pre-swizzled source element offset

    const short* aG0 = Ag + (size_t)(wid * 8 + rl) * lda + kx;
    const short* bG0 = Bg + (size_t)(wid * 8 + rl) * ldb + kx;
    size_t aCs = (size_t)32 * lda;  // chunk stride = 32 rows (FIXED)
    size_t bCs = (size_t)32 * ldb;
    short* aL0 = Alds + wid * 512;  // 8 rows x 64 shorts per wave-chunk
    short* bL0 = Blds + wid * 512;

    for (int k0 = 0; k0 < K; k0 += 64) {
        gload16(aG0 + k0, aL0);
        gload16(aG0 + aCs + k0, aL0 + 2048);
        gload16(aG0 + 2 * aCs + k0, aL0 + 4096);
        gload16(aG0 + 3 * aCs + k0, aL0 + 6144);
        gload16(bG0 + k0, bL0);
        gload16(bG0 + bCs + k0, bL0 + 2048);
        __syncthreads(); // drains vmcnt(0): staged data visible
#pragma unroll
        for (int kk = 0; kk < 2; ++kk) {
            int x = kk * 64 + ((lane >> 4) << 4);
            short8 af[4], bf_[2];
#pragma unroll
            for (int i = 0; i < 4; ++i) {
                int row = wm * 64 + i * 16 + l15;
                af[i] = *(const short8*)((const char*)Alds + row * 128 + (x ^ ((row & 7) << 4)));
            }
#pragma unroll
            for (int j = 0; j < 2; ++j) {
                int row = wn * 32 + j * 16 + l15;
                bf_[j] = *(const short8*)((const char*)Blds + row * 128 + (x ^ ((row & 7) << 4)));
            }
            mm42(acc, af, bf_);
        }
        __syncthreads(); // LDS reuse
    }
}

// ---------------------------------------------------------------------------
// projn: t<512: K/V projection via m97 core (128x64 tiles); t>=512: q (old).
__global__ void __launch_bounds__(256, 2)
projn(const short* __restrict__ toks_bf,
      const short* __restrict__ Wk_bf,
      const short* __restrict__ Wv_bf,
      const short* __restrict__ ev_bf,
      const short* __restrict__ Wq_bf,
      const float* __restrict__ bk, const float* __restrict__ bv,
      const float* __restrict__ bq,
      short* __restrict__ K_bf, short* __restrict__ V_bf,
      short* __restrict__ q_bf) {
    __shared__ short Alds[128 * 64];
    __shared__ short Blds[64 * 64];
    int t = blockIdx.x;
    int tid = threadIdx.x, lane = tid & 63, wid = tid >> 6;
    int l15 = lane & 15;
    int crow = (lane >> 4) * 4;

    if (t < 512) {
        int l = swz8(t, 64); // b*64 + kind*32 + mt*8 + nt
        int b = l >> 6, kind = (l >> 5) & 1, mt = (l >> 3) & 3, nt = l & 7;
        const short* Ag = toks_bf + (size_t)(b * SL + mt * 128) * NH;
        const short* Bg = (kind ? Wv_bf : Wk_bf) + (size_t)(nt * 64) * NH;
        const float* bias = kind ? bv : bk;
        short* dst = kind ? V_bf : K_bf;

        f32x4 acc[4][2];
#pragma unroll
        for (int i = 0; i < 4; ++i)
#pragma unroll
            for (int j = 0; j < 2; ++j) acc[i][j] = (f32x4)0.f;

        m97_core(Ag, NH, Bg, NH, NH, Alds, Blds, wid, lane, acc);

        int wm = wid >> 1, wn = wid & 1;
#pragma unroll
        for (int i = 0; i < 4; ++i)
#pragma unroll
            for (int j = 0; j < 2; ++j) {
                int col = nt * 64 + wn * 32 + j * 16 + l15;
                float bval = bias[col];
                int row0 = b * SL + mt * 128 + wm * 64 + i * 16 + crow;
#pragma unroll
                for (int r = 0; r < 4; ++r)
                    dst[(size_t)(row0 + r) * NH + col] = f2b(acc[i][j][r] + bval);
            }
    } else {
        // q projection: M=64, N=512 over 4 blocks; wave = 64e x 32cols.
        int tq = t - 512;
        int kb = (lane >> 4) * 8;
        int n0 = tq * 128 + wid * 32;
        const short* A = ev_bf + (size_t)l15 * NH + kb;
        const short* B = Wq_bf + (size_t)(n0 + l15) * NH + kb;

        f32x4 acc[4][2];
#pragma unroll
        for (int i = 0; i < 4; ++i)
#pragma unroll
            for (int j = 0; j < 2; ++j) acc[i][j] = (f32x4)0.f;

        for (int k = 0; k < NH; k += 32) {
            short8 a[4], bb[2];
#pragma unroll
            for (int i = 0; i < 4; ++i) a[i] = *(const short8*)(A + (size_t)i * 16 * NH + k);
#pragma unroll
            for (int j = 0; j < 2; ++j) bb[j] = *(const short8*)(B + (size_t)j * 16 * NH + k);
            mm42(acc, a, bb);
        }

#pragma unroll
        for (int i = 0; i < 4; ++i)
#pragma unroll
            for (int j = 0; j < 2; ++j) {
                int col = n0 + j * 16 + l15;
                float bval = bq[col];
#pragma unroll
                for (int r = 0; r < 4; ++r)
                    q_bf[(size_t)(i * 16 + crow + r) * NH + col] = f2b((acc[i][j][r] + bval) * SCALE);
            }
    }
}

// ---------------------------------------------------------------------------
// scores: S_bf[b][h][e][s] = EXP(q_scaled[e] . K[b][s]) bf16. grid 64. (old)
__global__ void __launch_bounds__(256, 2)
scores_mfma(const short* __restrict__ q_bf,
            const short* __restrict__ K_bf,
            short* __restrict__ S_bf) {
    int l = swz8(blockIdx.x, 8);
    int b = l >> 3, h = (l >> 2) & 1, st = l & 3;
    int tid = threadIdx.x, lane = tid & 63, wid = tid >> 6;
    int l15 = lane & 15;
    int n0 = st * 128 + wid * 32;
    int kb = (lane >> 4) * 8;

    f32x4 acc[4][2];
#pragma unroll
    for (int i = 0; i < 4; ++i)
#pragma unroll
        for (int j = 0; j < 2; ++j) acc[i][j] = (f32x4)0.f;

    const short* Aq = q_bf + (size_t)l15 * NH + h * DH + kb;
    const short* Bk = K_bf + ((size_t)b * SL + n0 + l15) * NH + h * DH + kb;

    short8 a0[4], a1[4];
    short8 b0[2], b1[2];
    ldg4(a0, Aq, 0, NH);
    ldg2(b0, Bk, 0, NH);
#pragma unroll
    for (int p = 0; p < 4; ++p) {
        int k1 = p * 64 + 32;
        ldg4(a1, Aq, k1, NH);
        ldg2(b1, Bk, k1, NH);
        mm42(acc, a0, b0);
        if (p < 3) {
            ldg4(a0, Aq, k1 + 32, NH);
            ldg2(b0, Bk, k1 + 32, NH);
        }
        mm42(acc, a1, b1);
    }

    int crow = (lane >> 4) * 4;
#pragma unroll
    for (int i = 0; i < 4; ++i)
#pragma unroll
        for (int j = 0; j < 2; ++j) {
            int col = n0 + j * 16 + l15;
#pragma unroll
            for (int r = 0; r < 4; ++r) {
                int row = i * 16 + crow + r;
                S_bf[(((size_t)(b * HEADS + h)) * NE + row) * SL + col] = f2b(__expf(acc[i][j][r]));
            }
        }
}

// ---------------------------------------------------------------------------
// vwtn: VWt2[b][o][h*512+s] = sum_d Wo[o][h*DH+d]*V[b][s][h*DH+d]. m97 core.
// grid 512: l = bh*32 + mt*8 + nt; per bh: M=512 (o) x N=512 (s), K=256.
__global__ void __launch_bounds__(256, 2)
vwtn(const short* __restrict__ V_bf,
     const short* __restrict__ Wo_bf,
     short* __restrict__ VWt) {
    __shared__ short Alds[128 * 64];
    __shared__ short Blds[64 * 64];
    int l = swz8(blockIdx.x, 64);
    int bh = l >> 5, mt = (l >> 3) & 3, nt = l & 7;
    int b = bh >> 1, h = bh & 1;
    int tid = threadIdx.x, lane = tid & 63, wid = tid >> 6;
    int l15 = lane & 15;
    int crow = (lane >> 4) * 4;

    const short* Ag = Wo_bf + (size_t)(mt * 128) * NH + h * DH;
    const short* Bg = V_bf + (size_t)(b * SL + nt * 64) * NH + h * DH;

    f32x4 acc[4][2];
#pragma unroll
    for (int i = 0; i < 4; ++i)
#pragma unroll
        for (int j = 0; j < 2; ++j) acc[i][j] = (f32x4)0.f;

    m97_core(Ag, NH, Bg, NH, DH, Alds, Blds, wid, lane, acc);

    int wm = wid >> 1, wn = wid & 1;
    short* dst = VWt + (size_t)b * NH * 1024 + h * 512;
#pragma unroll
    for (int i = 0; i < 4; ++i)
#pragma unroll
        for (int j = 0; j < 2; ++j) {
            int col = nt * 64 + wn * 32 + j * 16 + l15;      // s
            int row0 = mt * 128 + wm * 64 + i * 16 + crow;   // o
#pragma unroll
            for (int r = 0; r < 4; ++r)
                dst[(size_t)(row0 + r) * 1024 + col] = f2b(acc[i][j][r]);
        }
}

// ---------------------------------------------------------------------------
// pnorm: P[(b*16+ent)*64+e][h*512+s] = mask ? expS*inv : 0. grid 256. (old)
__global__ void __launch_bounds__(256, 4)
pnorm_kernel(const short* __restrict__ S_bf,
             const void* __restrict__ ents,
             const int* __restrict__ flag,
             short* __restrict__ P) {
    int l = swz8(blockIdx.x, 32); // b*32 + ent*2 + eh
    int b = l >> 5, ent = (l >> 1) & 15, eh = l & 1;
    int tid = threadIdx.x, lane = tid & 63, wid = tid >> 6;

    unsigned att8 = 0;
    {
        size_t mbase = ((size_t)b * EN + ent) * SL + lane * 8;
        if (flag[0]) {
            const int* p = (const int*)ents;
#pragma unroll
            for (int j = 0; j < 8; ++j)
                if (p[mbase + j]) att8 |= 1u << j;
        } else {
            const unsigned char* p = (const unsigned char*)ents;
#pragma unroll
            for (int j = 0; j < 8; ++j)
                if (p[mbase + j]) att8 |= 1u << j;
        }
    }

    for (int it = 0; it < 8; ++it) {
        int e = eh * 32 + wid * 8 + it;
        const short* s0p = S_bf + (((size_t)(b * HEADS + 0)) * NE + e) * SL + lane * 8;
        const short* s1p = S_bf + (((size_t)(b * HEADS + 1)) * NE + e) * SL + lane * 8;
        short8 v0 = *(const short8*)s0p;
        short8 v1 = *(const short8*)s1p;
        float f0[8], f1[8], sum0 = 0.f, sum1 = 0.f;
#pragma unroll
        for (int j = 0; j < 8; ++j) {
            f0[j] = (att8 >> j & 1) ? b2f(v0[j]) : 0.f;
            f1[j] = (att8 >> j & 1) ? b2f(v1[j]) : 0.f;
            sum0 += f0[j];
            sum1 += f1[j];
        }
#pragma unroll
        for (int off = 32; off; off >>= 1) {
            sum0 += __shfl_xor(sum0, off);
            sum1 += __shfl_xor(sum1, off);
        }
        float iv0 = 1.f / sum0, iv1 = 1.f / sum1;
        short8 o0, o1;
#pragma unroll
        for (int j = 0; j < 8; ++j) {
            o0[j] = f2b(f0[j] * iv0);
            o1[j] = f2b(f1[j] * iv1);
        }
        short* prow = P + ((size_t)(b * EN + ent) * NE + e) * 1024;
        *(short8*)(prow + lane * 8) = o0;
        *(short8*)(prow + 512 + lane * 8) = o1;
    }
}

// ---------------------------------------------------------------------------
// outg: out = P @ VWt2^T + bo. M=8192, N=512, K=1024. m97 core, grid 512:
// l = b*64 + mt*8 + nt (mt: 8 x 128 rows of the batch's 1024; nt: 8 x 64).
__global__ void __launch_bounds__(256, 2)
outg(const short* __restrict__ P,
     const short* __restrict__ VWt,
     const float* __restrict__ bo,
     float* __restrict__ out) {
    __shared__ short Alds[128 * 64];
    __shared__ short Blds[64 * 64];
    int l = swz8(blockIdx.x, 64);
    int b = l >> 6, mt = (l >> 3) & 7, nt = l & 7;
    int tid = threadIdx.x, lane = tid & 63, wid = tid >> 6;
    int l15 = lane & 15;
    int crow = (lane >> 4) * 4;

    const short* Ag = P + ((size_t)b * 1024 + mt * 128) * 1024;
    const short* Bg = VWt + ((size_t)b * NH + nt * 64) * 1024;

    f32x4 acc[4][2];
#pragma unroll
    for (int i = 0; i < 4; ++i)
#pragma unroll
        for (int j = 0; j < 2; ++j) acc[i][j] = (f32x4)0.f;

    m97_core(Ag, 1024, Bg, 1024, 1024, Alds, Blds, wid, lane, acc);

    int wm = wid >> 1, wn = wid & 1;
    int gr0 = b * 1024 + mt * 128 + wm * 64;
#pragma unroll
    for (int i = 0; i < 4; ++i)
#pragma unroll
        for (int j = 0; j < 2; ++j) {
            int col = nt * 64 + wn * 32 + j * 16 + l15;
            float bval = bo[col];
#pragma unroll
            for (int r = 0; r < 4; ++r) {
                int row = gr0 + i * 16 + crow + r;
                out[(size_t)row * NH + col] = acc[i][j][r] + bval;
            }
        }
}

// ---------------------------------------------------------------------------
extern "C" void kernel_launch(void* const* d_in, const int* in_sizes, int n_in,
                              void* d_out, int out_size, void* d_ws, size_t ws_size,
                              hipStream_t stream) {
    const float* toks = (const float*)d_in[0];
    const void* ents = d_in[1];
    const float* evs = (const float*)d_in[2];
    const float* Wq = (const float*)d_in[6];
    const float* Wk = (const float*)d_in[7];
    const float* Wv = (const float*)d_in[8];
    const float* bq = (const float*)d_in[9];
    const float* bk = (const float*)d_in[10];
    const float* bv = (const float*)d_in[11];
    const float* Wo = (const float*)d_in[12];
    const float* bo = (const float*)d_in[13];

    char* ws = (char*)d_ws;
    short* toks_bf = (short*)(ws + WS_TOKS);
    short* K_bf = (short*)(ws + WS_K);
    short* V_bf = (short*)(ws + WS_V);
    short* S_bf = (short*)(ws + WS_S);
    short* Wk_bf = (short*)(ws + WS_WK);
    short* Wv_bf = (short*)(ws + WS_WV);
    short* Wo_bf = (short*)(ws + WS_WO);
    short* Wq_bf = (short*)(ws + WS_WQ);
    short* ev_bf = (short*)(ws + WS_EV);
    short* q_bf = (short*)(ws + WS_Q);
    int* flag = (int*)(ws + WS_FLAG);
    short* VWt = (short*)(ws + WS_VW);
    short* P = (short*)(ws + WS_P);

    prep_kernel<<<CH_TOTAL / 256 + 1, 256, 0, stream>>>(
        toks, Wk, Wv, Wo, Wq, evs, (const unsigned char*)ents,
        toks_bf, Wk_bf, Wv_bf, Wo_bf, Wq_bf, ev_bf, flag);
    projn<<<516, 256, 0, stream>>>(toks_bf, Wk_bf, Wv_bf, ev_bf, Wq_bf,
                                   bk, bv, bq, K_bf, V_bf, q_bf);
    scores_mfma<<<64, 256, 0, stream>>>(q_bf, K_bf, S_bf);
    vwtn<<<512, 256, 0, stream>>>(V_bf, Wo_bf, VWt);
    pnorm_kernel<<<256, 256, 0, stream>>>(S_bf, ents, flag, P);
    outg<<<512, 256, 0, stream>>>(P, VWt, bo, (float*)d_out);
}

// Round 19
// 69.742 us; speedup vs baseline: 1.5949x; 1.0441x over previous
//
#include <hip/hip_runtime.h>

// EntityAttention — round 19: R18 with the workspace aliasing fixed.
// ROOT CAUSE of R17/R18 failures: WS_EV/WS_Q (24MB) aliased WS_VW (24MB);
// merging scores into the vwtn launch made vwtn clobber q_bf while scores
// blocks read it. VWt moved to 32MB. Logic otherwise identical to R16/R18.
// NB=8 SL=512 NH=512 EN=16 NE=64 HEADS=2 DH=256.

#define NB 8
#define SL 512
#define NH 512
#define EN 16
#define NE 64
#define HEADS 2
#define DH 256
#define SCALE 0.0625f

typedef __attribute__((ext_vector_type(8))) short short8;
typedef __attribute__((ext_vector_type(4))) short short4v;
typedef __attribute__((ext_vector_type(4))) float f32x4;

#define MFMA16(a, b, c) __builtin_amdgcn_mfma_f32_16x16x32_bf16(a, b, c, 0, 0, 0)

__device__ __forceinline__ short f2b(float f) {
    unsigned u = __builtin_bit_cast(unsigned, f);
    u += 0x7fffu + ((u >> 16) & 1u);
    return (short)(u >> 16);
}
__device__ __forceinline__ float b2f(short s) {
    return __builtin_bit_cast(float, ((unsigned)(unsigned short)s) << 16);
}
__device__ __forceinline__ int swz8(int hw, int chunk) {
    return (hw & 7) * chunk + (hw >> 3);
}

// async global->LDS, 16B per lane; HW writes lane l at ldsbase + l*16.
__device__ __forceinline__ void gload16(const short* g, short* l) {
    __builtin_amdgcn_global_load_lds(
        (const __attribute__((address_space(1))) unsigned int*)g,
        (__attribute__((address_space(3))) unsigned int*)l, 16, 0, 0);
}

__device__ __forceinline__ void ldg4(short8 (&d)[4], const short* p, int k, int stride) {
#pragma unroll
    for (int j = 0; j < 4; ++j) d[j] = *(const short8*)(p + (size_t)j * 16 * stride + k);
}
__device__ __forceinline__ void ldg2(short8 (&d)[2], const short* p, int k, int stride) {
#pragma unroll
    for (int j = 0; j < 2; ++j) d[j] = *(const short8*)(p + (size_t)j * 16 * stride + k);
}
__device__ __forceinline__ void mm42(f32x4 (&acc)[4][2], const short8 (&a)[4], const short8 (&bb)[2]) {
#pragma unroll
    for (int i = 0; i < 4; ++i)
#pragma unroll
        for (int j = 0; j < 2; ++j) acc[i][j] = MFMA16(a[i], bb[j], acc[i][j]);
}

// ---- ws byte offsets (VWt moved past all weight/q buffers) -----------------
#define WS_TOKS 0u
#define WS_K (4u << 20)
#define WS_V (8u << 20)
#define WS_S (20u << 20)
#define WS_WK (22u << 20)
#define WS_WV (WS_WK + (512u << 10))
#define WS_WO (WS_WV + (512u << 10))
#define WS_WQ (WS_WO + (512u << 10))
#define WS_EV (WS_WQ + (512u << 10))
#define WS_Q (WS_EV + (64u << 10))
#define WS_FLAG (WS_Q + (64u << 10))
#define WS_VW (32u << 20)  /* VWt2[b][o][h*512+s]: 32..40 MB (no aliasing) */
#define WS_P (40u << 20)   /* P[slot][e][1024]: 40..56.8 MB */

#define CH_TOKS (NB * SL * NH / 4)
#define CH_W (NH * NH / 4)
#define CH_EV (NE * NH / 4)
#define CH_TOTAL (CH_TOKS + 4 * CH_W + CH_EV)

// ---------------------------------------------------------------------------
__global__ void prep_kernel(const float* __restrict__ toks, const float* __restrict__ Wk,
                            const float* __restrict__ Wv, const float* __restrict__ Wo,
                            const float* __restrict__ Wq, const float* __restrict__ ev,
                            const unsigned char* __restrict__ ents,
                            short* __restrict__ toks_bf, short* __restrict__ Wk_bf,
                            short* __restrict__ Wv_bf, short* __restrict__ Wo_bf,
                            short* __restrict__ Wq_bf, short* __restrict__ ev_bf,
                            int* __restrict__ flag) {
    __shared__ int red[256];
    int idx = blockIdx.x * 256 + threadIdx.x;
    if (idx < CH_TOTAL) {
        const float* src;
        short* dst;
        int off = idx;
        if (idx < CH_TOKS) { src = toks; dst = toks_bf; }
        else if (idx < CH_TOKS + CH_W) { src = Wk; dst = Wk_bf; off -= CH_TOKS; }
        else if (idx < CH_TOKS + 2 * CH_W) { src = Wv; dst = Wv_bf; off -= CH_TOKS + CH_W; }
        else if (idx < CH_TOKS + 3 * CH_W) { src = Wo; dst = Wo_bf; off -= CH_TOKS + 2 * CH_W; }
        else if (idx < CH_TOKS + 4 * CH_W) { src = Wq; dst = Wq_bf; off -= CH_TOKS + 3 * CH_W; }
        else { src = ev; dst = ev_bf; off -= CH_TOKS + 4 * CH_W; }
        f32x4 v = ((const f32x4*)src)[off];
        short4v o;
#pragma unroll
        for (int j = 0; j < 4; ++j) o[j] = f2b(v[j]);
        ((short4v*)dst)[off] = o;
    }
    if (blockIdx.x == gridDim.x - 1) {
        int tid = threadIdx.x;
        int cnt = 0;
        for (int j = 0; j < 16; ++j) {
            int off = tid * 16 + j;
            if ((off & 3) != 0 && ents[off] != 0) cnt++;
        }
        red[tid] = cnt;
        __syncthreads();
        for (int s = 128; s > 0; s >>= 1) {
            if (tid < s) red[tid] += red[tid + s];
            __syncthreads();
        }
        if (tid == 0) flag[0] = (red[0] == 0) ? 1 : 0;
    }
}

// ---------------------------------------------------------------------------
// m97-style core: one 128x64 C-tile, 4 waves (64x32 each), BK=64.
// LDS linear [row][64 elem]; content column-swizzled: LDS[row] byte x holds
// src[row] byte x ^ ((row&7)<<4) -> conflict-free ds_read_b128.
__device__ __forceinline__ void m97_core(
    const short* __restrict__ Ag, int lda,
    const short* __restrict__ Bg, int ldb, int K,
    short* Alds, short* Blds, int wid, int lane, f32x4 (&acc)[4][2]) {
    int wm = wid >> 1, wn = wid & 1;
    int l15 = lane & 15;
    int rl = lane >> 3;             // 0..7: row within this wave's 8-row chunk
    int xb = (lane & 7) << 4;       // byte 0..112 within the 128B row
    int kx = (xb ^ (rl << 4)) >> 1; // pre-swizzled source element offset

    const short* aG0 = Ag + (size_t)(wid * 8 + rl) * lda + kx;
    const short* bG0 = Bg + (size_t)(wid * 8 + rl) * ldb + kx;
    size_t aCs = (size_t)32 * lda;  // chunk stride = 32 rows
    size_t bCs = (size_t)32 * ldb;
    short* aL0 = Alds + wid * 512;  // 8 rows x 64 shorts per wave-chunk
    short* bL0 = Blds + wid * 512;

    for (int k0 = 0; k0 < K; k0 += 64) {
        gload16(aG0 + k0, aL0);
        gload16(aG0 + aCs + k0, aL0 + 2048);
        gload16(aG0 + 2 * aCs + k0, aL0 + 4096);
        gload16(aG0 + 3 * aCs + k0, aL0 + 6144);
        gload16(bG0 + k0, bL0);
        gload16(bG0 + bCs + k0, bL0 + 2048);
        __syncthreads(); // drains vmcnt(0): staged data visible
#pragma unroll
        for (int kk = 0; kk < 2; ++kk) {
            int x = kk * 64 + ((lane >> 4) << 4);
            short8 af[4], bf_[2];
#pragma unroll
            for (int i = 0; i < 4; ++i) {
                int row = wm * 64 + i * 16 + l15;
                af[i] = *(const short8*)((const char*)Alds + row * 128 + (x ^ ((row & 7) << 4)));
            }
#pragma unroll
            for (int j = 0; j < 2; ++j) {
                int row = wn * 32 + j * 16 + l15;
                bf_[j] = *(const short8*)((const char*)Blds + row * 128 + (x ^ ((row & 7) << 4)));
            }
            mm42(acc, af, bf_);
        }
        __syncthreads(); // LDS reuse
    }
}

// ---------------------------------------------------------------------------
// projn: t<512: K/V projection via m97 core (128x64 tiles); t>=512: q (old).
__global__ void __launch_bounds__(256, 2)
projn(const short* __restrict__ toks_bf,
      const short* __restrict__ Wk_bf,
      const short* __restrict__ Wv_bf,
      const short* __restrict__ ev_bf,
      const short* __restrict__ Wq_bf,
      const float* __restrict__ bk, const float* __restrict__ bv,
      const float* __restrict__ bq,
      short* __restrict__ K_bf, short* __restrict__ V_bf,
      short* __restrict__ q_bf) {
    __shared__ short Alds[128 * 64];
    __shared__ short Blds[64 * 64];
    int t = blockIdx.x;
    int tid = threadIdx.x, lane = tid & 63, wid = tid >> 6;
    int l15 = lane & 15;
    int crow = (lane >> 4) * 4;

    if (t < 512) {
        int l = swz8(t, 64); // b*64 + kind*32 + mt*8 + nt
        int b = l >> 6, kind = (l >> 5) & 1, mt = (l >> 3) & 3, nt = l & 7;
        const short* Ag = toks_bf + (size_t)(b * SL + mt * 128) * NH;
        const short* Bg = (kind ? Wv_bf : Wk_bf) + (size_t)(nt * 64) * NH;
        const float* bias = kind ? bv : bk;
        short* dst = kind ? V_bf : K_bf;

        f32x4 acc[4][2];
#pragma unroll
        for (int i = 0; i < 4; ++i)
#pragma unroll
            for (int j = 0; j < 2; ++j) acc[i][j] = (f32x4)0.f;

        m97_core(Ag, NH, Bg, NH, NH, Alds, Blds, wid, lane, acc);

        int wm = wid >> 1, wn = wid & 1;
#pragma unroll
        for (int i = 0; i < 4; ++i)
#pragma unroll
            for (int j = 0; j < 2; ++j) {
                int col = nt * 64 + wn * 32 + j * 16 + l15;
                float bval = bias[col];
                int row0 = b * SL + mt * 128 + wm * 64 + i * 16 + crow;
#pragma unroll
                for (int r = 0; r < 4; ++r)
                    dst[(size_t)(row0 + r) * NH + col] = f2b(acc[i][j][r] + bval);
            }
    } else {
        // q projection: M=64, N=512 over 4 blocks; wave = 64e x 32cols.
        int tq = t - 512;
        int kb = (lane >> 4) * 8;
        int n0 = tq * 128 + wid * 32;
        const short* A = ev_bf + (size_t)l15 * NH + kb;
        const short* B = Wq_bf + (size_t)(n0 + l15) * NH + kb;

        f32x4 acc[4][2];
#pragma unroll
        for (int i = 0; i < 4; ++i)
#pragma unroll
            for (int j = 0; j < 2; ++j) acc[i][j] = (f32x4)0.f;

        for (int k = 0; k < NH; k += 32) {
            short8 a[4], bb[2];
#pragma unroll
            for (int i = 0; i < 4; ++i) a[i] = *(const short8*)(A + (size_t)i * 16 * NH + k);
#pragma unroll
            for (int j = 0; j < 2; ++j) bb[j] = *(const short8*)(B + (size_t)j * 16 * NH + k);
            mm42(acc, a, bb);
        }

#pragma unroll
        for (int i = 0; i < 4; ++i)
#pragma unroll
            for (int j = 0; j < 2; ++j) {
                int col = n0 + j * 16 + l15;
                float bval = bq[col];
#pragma unroll
                for (int r = 0; r < 4; ++r)
                    q_bf[(size_t)(i * 16 + crow + r) * NH + col] = f2b((acc[i][j][r] + bval) * SCALE);
            }
    }
}

// ---------------------------------------------------------------------------
// vwtn_scores: t<512: VWt2 tiles (m97 core). t>=512 (64 blocks): scores
// (expS, register path) — hidden under the vwtn tiles. Safe now: VWt no
// longer aliases q_bf/ev_bf.
__global__ void __launch_bounds__(256, 2)
vwtn_scores(const short* __restrict__ V_bf,
            const short* __restrict__ Wo_bf,
            const short* __restrict__ q_bf,
            const short* __restrict__ K_bf,
            short* __restrict__ VWt,
            short* __restrict__ S_bf) {
    __shared__ short Alds[128 * 64];
    __shared__ short Blds[64 * 64];
    int t = blockIdx.x;
    int tid = threadIdx.x, lane = tid & 63, wid = tid >> 6;
    int l15 = lane & 15;
    int crow = (lane >> 4) * 4;

    if (t < 512) {
        int l = swz8(t, 64); // bh*32 + mt*8 + nt
        int bh = l >> 5, mt = (l >> 3) & 3, nt = l & 7;
        int b = bh >> 1, h = bh & 1;

        const short* Ag = Wo_bf + (size_t)(mt * 128) * NH + h * DH;
        const short* Bg = V_bf + (size_t)(b * SL + nt * 64) * NH + h * DH;

        f32x4 acc[4][2];
#pragma unroll
        for (int i = 0; i < 4; ++i)
#pragma unroll
            for (int j = 0; j < 2; ++j) acc[i][j] = (f32x4)0.f;

        m97_core(Ag, NH, Bg, NH, DH, Alds, Blds, wid, lane, acc);

        int wm = wid >> 1, wn = wid & 1;
        short* dst = VWt + (size_t)b * NH * 1024 + h * 512;
#pragma unroll
        for (int i = 0; i < 4; ++i)
#pragma unroll
            for (int j = 0; j < 2; ++j) {
                int col = nt * 64 + wn * 32 + j * 16 + l15;      // s
                int row0 = mt * 128 + wm * 64 + i * 16 + crow;   // o
#pragma unroll
                for (int r = 0; r < 4; ++r)
                    dst[(size_t)(row0 + r) * 1024 + col] = f2b(acc[i][j][r]);
            }
    } else {
        // scores: S_bf[b][h][e][s] = EXP(q . K). 64 blocks (register path).
        int l = swz8(t - 512, 8); // b*8 + h*4 + st
        int b = l >> 3, h = (l >> 2) & 1, st = l & 3;
        int n0 = st * 128 + wid * 32;
        int kb = (lane >> 4) * 8;

        f32x4 acc[4][2];
#pragma unroll
        for (int i = 0; i < 4; ++i)
#pragma unroll
            for (int j = 0; j < 2; ++j) acc[i][j] = (f32x4)0.f;

        const short* Aq = q_bf + (size_t)l15 * NH + h * DH + kb;
        const short* Bk = K_bf + ((size_t)b * SL + n0 + l15) * NH + h * DH + kb;

        short8 a0[4], a1[4];
        short8 b0[2], b1[2];
        ldg4(a0, Aq, 0, NH);
        ldg2(b0, Bk, 0, NH);
#pragma unroll
        for (int p = 0; p < 4; ++p) {
            int k1 = p * 64 + 32;
            ldg4(a1, Aq, k1, NH);
            ldg2(b1, Bk, k1, NH);
            mm42(acc, a0, b0);
            if (p < 3) {
                ldg4(a0, Aq, k1 + 32, NH);
                ldg2(b0, Bk, k1 + 32, NH);
            }
            mm42(acc, a1, b1);
        }

#pragma unroll
        for (int i = 0; i < 4; ++i)
#pragma unroll
            for (int j = 0; j < 2; ++j) {
                int col = n0 + j * 16 + l15;
#pragma unroll
                for (int r = 0; r < 4; ++r) {
                    int row = i * 16 + crow + r;
                    S_bf[(((size_t)(b * HEADS + h)) * NE + row) * SL + col] = f2b(__expf(acc[i][j][r]));
                }
            }
    }
}

// ---------------------------------------------------------------------------
// pnorm: P[(b*16+ent)*64+e][h*512+s] = mask ? expS*inv : 0. grid 256.
__global__ void __launch_bounds__(256, 4)
pnorm_kernel(const short* __restrict__ S_bf,
             const void* __restrict__ ents,
             const int* __restrict__ flag,
             short* __restrict__ P) {
    int l = swz8(blockIdx.x, 32); // b*32 + ent*2 + eh
    int b = l >> 5, ent = (l >> 1) & 15, eh = l & 1;
    int tid = threadIdx.x, lane = tid & 63, wid = tid >> 6;

    unsigned att8 = 0;
    {
        size_t mbase = ((size_t)b * EN + ent) * SL + lane * 8;
        if (flag[0]) {
            const int* p = (const int*)ents;
#pragma unroll
            for (int j = 0; j < 8; ++j)
                if (p[mbase + j]) att8 |= 1u << j;
        } else {
            const unsigned char* p = (const unsigned char*)ents;
#pragma unroll
            for (int j = 0; j < 8; ++j)
                if (p[mbase + j]) att8 |= 1u << j;
        }
    }

    for (int it = 0; it < 8; ++it) {
        int e = eh * 32 + wid * 8 + it;
        const short* s0p = S_bf + (((size_t)(b * HEADS + 0)) * NE + e) * SL + lane * 8;
        const short* s1p = S_bf + (((size_t)(b * HEADS + 1)) * NE + e) * SL + lane * 8;
        short8 v0 = *(const short8*)s0p;
        short8 v1 = *(const short8*)s1p;
        float f0[8], f1[8], sum0 = 0.f, sum1 = 0.f;
#pragma unroll
        for (int j = 0; j < 8; ++j) {
            f0[j] = (att8 >> j & 1) ? b2f(v0[j]) : 0.f;
            f1[j] = (att8 >> j & 1) ? b2f(v1[j]) : 0.f;
            sum0 += f0[j];
            sum1 += f1[j];
        }
#pragma unroll
        for (int off = 32; off; off >>= 1) {
            sum0 += __shfl_xor(sum0, off);
            sum1 += __shfl_xor(sum1, off);
        }
        float iv0 = 1.f / sum0, iv1 = 1.f / sum1;
        short8 o0, o1;
#pragma unroll
        for (int j = 0; j < 8; ++j) {
            o0[j] = f2b(f0[j] * iv0);
            o1[j] = f2b(f1[j] * iv1);
        }
        short* prow = P + ((size_t)(b * EN + ent) * NE + e) * 1024;
        *(short8*)(prow + lane * 8) = o0;
        *(short8*)(prow + 512 + lane * 8) = o1;
    }
}

// ---------------------------------------------------------------------------
// outg: out = P @ VWt2^T + bo. M=8192, N=512, K=1024. m97 core, grid 512.
__global__ void __launch_bounds__(256, 2)
outg(const short* __restrict__ P,
     const short* __restrict__ VWt,
     const float* __restrict__ bo,
     float* __restrict__ out) {
    __shared__ short Alds[128 * 64];
    __shared__ short Blds[64 * 64];
    int l = swz8(blockIdx.x, 64);
    int b = l >> 6, mt = (l >> 3) & 7, nt = l & 7;
    int tid = threadIdx.x, lane = tid & 63, wid = tid >> 6;
    int l15 = lane & 15;
    int crow = (lane >> 4) * 4;

    const short* Ag = P + ((size_t)b * 1024 + mt * 128) * 1024;
    const short* Bg = VWt + ((size_t)b * NH + nt * 64) * 1024;

    f32x4 acc[4][2];
#pragma unroll
    for (int i = 0; i < 4; ++i)
#pragma unroll
        for (int j = 0; j < 2; ++j) acc[i][j] = (f32x4)0.f;

    m97_core(Ag, 1024, Bg, 1024, 1024, Alds, Blds, wid, lane, acc);

    int wm = wid >> 1, wn = wid & 1;
    int gr0 = b * 1024 + mt * 128 + wm * 64;
#pragma unroll
    for (int i = 0; i < 4; ++i)
#pragma unroll
        for (int j = 0; j < 2; ++j) {
            int col = nt * 64 + wn * 32 + j * 16 + l15;
            float bval = bo[col];
#pragma unroll
            for (int r = 0; r < 4; ++r) {
                int row = gr0 + i * 16 + crow + r;
                out[(size_t)row * NH + col] = acc[i][j][r] + bval;
            }
        }
}

// ---------------------------------------------------------------------------
extern "C" void kernel_launch(void* const* d_in, const int* in_sizes, int n_in,
                              void* d_out, int out_size, void* d_ws, size_t ws_size,
                              hipStream_t stream) {
    const float* toks = (const float*)d_in[0];
    const void* ents = d_in[1];
    const float* evs = (const float*)d_in[2];
    const float* Wq = (const float*)d_in[6];
    const float* Wk = (const float*)d_in[7];
    const float* Wv = (const float*)d_in[8];
    const float* bq = (const float*)d_in[9];
    const float* bk = (const float*)d_in[10];
    const float* bv = (const float*)d_in[11];
    const float* Wo = (const float*)d_in[12];
    const float* bo = (const float*)d_in[13];

    char* ws = (char*)d_ws;
    short* toks_bf = (short*)(ws + WS_TOKS);
    short* K_bf = (short*)(ws + WS_K);
    short* V_bf = (short*)(ws + WS_V);
    short* S_bf = (short*)(ws + WS_S);
    short* Wk_bf = (short*)(ws + WS_WK);
    short* Wv_bf = (short*)(ws + WS_WV);
    short* Wo_bf = (short*)(ws + WS_WO);
    short* Wq_bf = (short*)(ws + WS_WQ);
    short* ev_bf = (short*)(ws + WS_EV);
    short* q_bf = (short*)(ws + WS_Q);
    int* flag = (int*)(ws + WS_FLAG);
    short* VWt = (short*)(ws + WS_VW);
    short* P = (short*)(ws + WS_P);

    prep_kernel<<<CH_TOTAL / 256 + 1, 256, 0, stream>>>(
        toks, Wk, Wv, Wo, Wq, evs, (const unsigned char*)ents,
        toks_bf, Wk_bf, Wv_bf, Wo_bf, Wq_bf, ev_bf, flag);
    projn<<<516, 256, 0, stream>>>(toks_bf, Wk_bf, Wv_bf, ev_bf, Wq_bf,
                                   bk, bv, bq, K_bf, V_bf, q_bf);
    vwtn_scores<<<576, 256, 0, stream>>>(V_bf, Wo_bf, q_bf, K_bf, VWt, S_bf);
    pnorm_kernel<<<256, 256, 0, stream>>>(S_bf, ents, flag, P);
    outg<<<512, 256, 0, stream>>>(P, VWt, bo, (float*)d_out);
}

// Round 20
// 67.452 us; speedup vs baseline: 1.6491x; 1.0340x over previous
//
#include <hip/hip_runtime.h>

// EntityAttention — round 20: R19 base (69.7 µs, aliasing-fixed) with the
// m97 core widened to 128x128 tiles (acc[4][4], 2x arithmetic intensity)
// for projn / vwtn / outg. prep / pnorm / scores unchanged.
// NB=8 SL=512 NH=512 EN=16 NE=64 HEADS=2 DH=256.

#define NB 8
#define SL 512
#define NH 512
#define EN 16
#define NE 64
#define HEADS 2
#define DH 256
#define SCALE 0.0625f

typedef __attribute__((ext_vector_type(8))) short short8;
typedef __attribute__((ext_vector_type(4))) short short4v;
typedef __attribute__((ext_vector_type(4))) float f32x4;

#define MFMA16(a, b, c) __builtin_amdgcn_mfma_f32_16x16x32_bf16(a, b, c, 0, 0, 0)

__device__ __forceinline__ short f2b(float f) {
    unsigned u = __builtin_bit_cast(unsigned, f);
    u += 0x7fffu + ((u >> 16) & 1u);
    return (short)(u >> 16);
}
__device__ __forceinline__ float b2f(short s) {
    return __builtin_bit_cast(float, ((unsigned)(unsigned short)s) << 16);
}
__device__ __forceinline__ int swz8(int hw, int chunk) {
    return (hw & 7) * chunk + (hw >> 3);
}

// async global->LDS, 16B per lane; HW writes lane l at ldsbase + l*16.
__device__ __forceinline__ void gload16(const short* g, short* l) {
    __builtin_amdgcn_global_load_lds(
        (const __attribute__((address_space(1))) unsigned int*)g,
        (__attribute__((address_space(3))) unsigned int*)l, 16, 0, 0);
}

__device__ __forceinline__ void ldg4(short8 (&d)[4], const short* p, int k, int stride) {
#pragma unroll
    for (int j = 0; j < 4; ++j) d[j] = *(const short8*)(p + (size_t)j * 16 * stride + k);
}
__device__ __forceinline__ void ldg2(short8 (&d)[2], const short* p, int k, int stride) {
#pragma unroll
    for (int j = 0; j < 2; ++j) d[j] = *(const short8*)(p + (size_t)j * 16 * stride + k);
}
__device__ __forceinline__ void mm42(f32x4 (&acc)[4][2], const short8 (&a)[4], const short8 (&bb)[2]) {
#pragma unroll
    for (int i = 0; i < 4; ++i)
#pragma unroll
        for (int j = 0; j < 2; ++j) acc[i][j] = MFMA16(a[i], bb[j], acc[i][j]);
}
__device__ __forceinline__ void mm44(f32x4 (&acc)[4][4], const short8 (&a)[4], const short8 (&bb)[4]) {
#pragma unroll
    for (int i = 0; i < 4; ++i)
#pragma unroll
        for (int j = 0; j < 4; ++j) acc[i][j] = MFMA16(a[i], bb[j], acc[i][j]);
}

// ---- ws byte offsets (aliasing-free layout from R19) -----------------------
#define WS_TOKS 0u
#define WS_K (4u << 20)
#define WS_V (8u << 20)
#define WS_S (20u << 20)
#define WS_WK (22u << 20)
#define WS_WV (WS_WK + (512u << 10))
#define WS_WO (WS_WV + (512u << 10))
#define WS_WQ (WS_WO + (512u << 10))
#define WS_EV (WS_WQ + (512u << 10))
#define WS_Q (WS_EV + (64u << 10))
#define WS_FLAG (WS_Q + (64u << 10))
#define WS_VW (32u << 20)  /* VWt2[b][o][h*512+s]: 32..40 MB */
#define WS_P (40u << 20)   /* P[slot][e][1024]: 40..56.8 MB */

#define CH_TOKS (NB * SL * NH / 4)
#define CH_W (NH * NH / 4)
#define CH_EV (NE * NH / 4)
#define CH_TOTAL (CH_TOKS + 4 * CH_W + CH_EV)

// ---------------------------------------------------------------------------
__global__ void prep_kernel(const float* __restrict__ toks, const float* __restrict__ Wk,
                            const float* __restrict__ Wv, const float* __restrict__ Wo,
                            const float* __restrict__ Wq, const float* __restrict__ ev,
                            const unsigned char* __restrict__ ents,
                            short* __restrict__ toks_bf, short* __restrict__ Wk_bf,
                            short* __restrict__ Wv_bf, short* __restrict__ Wo_bf,
                            short* __restrict__ Wq_bf, short* __restrict__ ev_bf,
                            int* __restrict__ flag) {
    __shared__ int red[256];
    int idx = blockIdx.x * 256 + threadIdx.x;
    if (idx < CH_TOTAL) {
        const float* src;
        short* dst;
        int off = idx;
        if (idx < CH_TOKS) { src = toks; dst = toks_bf; }
        else if (idx < CH_TOKS + CH_W) { src = Wk; dst = Wk_bf; off -= CH_TOKS; }
        else if (idx < CH_TOKS + 2 * CH_W) { src = Wv; dst = Wv_bf; off -= CH_TOKS + CH_W; }
        else if (idx < CH_TOKS + 3 * CH_W) { src = Wo; dst = Wo_bf; off -= CH_TOKS + 2 * CH_W; }
        else if (idx < CH_TOKS + 4 * CH_W) { src = Wq; dst = Wq_bf; off -= CH_TOKS + 3 * CH_W; }
        else { src = ev; dst = ev_bf; off -= CH_TOKS + 4 * CH_W; }
        f32x4 v = ((const f32x4*)src)[off];
        short4v o;
#pragma unroll
        for (int j = 0; j < 4; ++j) o[j] = f2b(v[j]);
        ((short4v*)dst)[off] = o;
    }
    if (blockIdx.x == gridDim.x - 1) {
        int tid = threadIdx.x;
        int cnt = 0;
        for (int j = 0; j < 16; ++j) {
            int off = tid * 16 + j;
            if ((off & 3) != 0 && ents[off] != 0) cnt++;
        }
        red[tid] = cnt;
        __syncthreads();
        for (int s = 128; s > 0; s >>= 1) {
            if (tid < s) red[tid] += red[tid + s];
            __syncthreads();
        }
        if (tid == 0) flag[0] = (red[0] == 0) ? 1 : 0;
    }
}

// ---------------------------------------------------------------------------
// m97 core, 128x128 tile: 4 waves of 64x64 (acc[4][4]), BK=64.
// LDS linear [row][64 shorts]; LDS[row] byte x holds src[row] byte
// x ^ ((row&7)<<4) -> conflict-free ds_read_b128 on both operands.
__device__ __forceinline__ void m97_core128(
    const short* __restrict__ Ag, int lda,
    const short* __restrict__ Bg, int ldb, int K,
    short* Alds, short* Blds, int wid, int lane, f32x4 (&acc)[4][4]) {
    int wm = wid >> 1, wn = wid & 1;
    int l15 = lane & 15;
    int rl = lane >> 3;             // 0..7: row within an 8-row chunk
    int xb = (lane & 7) << 4;       // byte 0..112 within the 128B row
    int kx = (xb ^ (rl << 4)) >> 1; // pre-swizzled source element offset

    const short* aG0 = Ag + (size_t)(wid * 8 + rl) * lda + kx;
    const short* bG0 = Bg + (size_t)(wid * 8 + rl) * ldb + kx;
    size_t aCs = (size_t)32 * lda;  // chunk stride = 32 rows
    size_t bCs = (size_t)32 * ldb;
    short* aL0 = Alds + wid * 512;  // wave's chunk-0 rows [wid*8, wid*8+8)
    short* bL0 = Blds + wid * 512;

    for (int k0 = 0; k0 < K; k0 += 64) {
#pragma unroll
        for (int c = 0; c < 4; ++c) {
            gload16(aG0 + c * aCs + k0, aL0 + c * 2048);
            gload16(bG0 + c * bCs + k0, bL0 + c * 2048);
        }
        __syncthreads(); // drains vmcnt(0): staged data visible
#pragma unroll
        for (int kk = 0; kk < 2; ++kk) {
            int x = kk * 64 + ((lane >> 4) << 4);
            short8 af[4], bf_[4];
#pragma unroll
            for (int i = 0; i < 4; ++i) {
                int row = wm * 64 + i * 16 + l15;
                af[i] = *(const short8*)((const char*)Alds + row * 128 + (x ^ ((row & 7) << 4)));
            }
#pragma unroll
            for (int j = 0; j < 4; ++j) {
                int row = wn * 64 + j * 16 + l15;
                bf_[j] = *(const short8*)((const char*)Blds + row * 128 + (x ^ ((row & 7) << 4)));
            }
            mm44(acc, af, bf_);
        }
        __syncthreads(); // LDS reuse
    }
}

// ---------------------------------------------------------------------------
// projn: t<256: K/V projection (128x128 tiles); t>=256 (4 blocks): q (old).
__global__ void __launch_bounds__(256, 2)
projn(const short* __restrict__ toks_bf,
      const short* __restrict__ Wk_bf,
      const short* __restrict__ Wv_bf,
      const short* __restrict__ ev_bf,
      const short* __restrict__ Wq_bf,
      const float* __restrict__ bk, const float* __restrict__ bv,
      const float* __restrict__ bq,
      short* __restrict__ K_bf, short* __restrict__ V_bf,
      short* __restrict__ q_bf) {
    __shared__ short Alds[128 * 64];
    __shared__ short Blds[128 * 64];
    int t = blockIdx.x;
    int tid = threadIdx.x, lane = tid & 63, wid = tid >> 6;
    int l15 = lane & 15;
    int crow = (lane >> 4) * 4;

    if (t < 256) {
        int l = swz8(t, 32); // b*32 + kind*16 + mt*4 + nt
        int b = l >> 5, kind = (l >> 4) & 1, mt = (l >> 2) & 3, nt = l & 3;
        const short* Ag = toks_bf + (size_t)(b * SL + mt * 128) * NH;
        const short* Bg = (kind ? Wv_bf : Wk_bf) + (size_t)(nt * 128) * NH;
        const float* bias = kind ? bv : bk;
        short* dst = kind ? V_bf : K_bf;

        f32x4 acc[4][4];
#pragma unroll
        for (int i = 0; i < 4; ++i)
#pragma unroll
            for (int j = 0; j < 4; ++j) acc[i][j] = (f32x4)0.f;

        m97_core128(Ag, NH, Bg, NH, NH, Alds, Blds, wid, lane, acc);

        int wm = wid >> 1, wn = wid & 1;
#pragma unroll
        for (int i = 0; i < 4; ++i)
#pragma unroll
            for (int j = 0; j < 4; ++j) {
                int col = nt * 128 + wn * 64 + j * 16 + l15;
                float bval = bias[col];
                int row0 = b * SL + mt * 128 + wm * 64 + i * 16 + crow;
#pragma unroll
                for (int r = 0; r < 4; ++r)
                    dst[(size_t)(row0 + r) * NH + col] = f2b(acc[i][j][r] + bval);
            }
    } else {
        // q projection: M=64, N=512 over 4 blocks; wave = 64e x 32cols.
        int tq = t - 256;
        int kb = (lane >> 4) * 8;
        int n0 = tq * 128 + wid * 32;
        const short* A = ev_bf + (size_t)l15 * NH + kb;
        const short* B = Wq_bf + (size_t)(n0 + l15) * NH + kb;

        f32x4 acc[4][2];
#pragma unroll
        for (int i = 0; i < 4; ++i)
#pragma unroll
            for (int j = 0; j < 2; ++j) acc[i][j] = (f32x4)0.f;

        for (int k = 0; k < NH; k += 32) {
            short8 a[4], bb[2];
#pragma unroll
            for (int i = 0; i < 4; ++i) a[i] = *(const short8*)(A + (size_t)i * 16 * NH + k);
#pragma unroll
            for (int j = 0; j < 2; ++j) bb[j] = *(const short8*)(B + (size_t)j * 16 * NH + k);
            mm42(acc, a, bb);
        }

#pragma unroll
        for (int i = 0; i < 4; ++i)
#pragma unroll
            for (int j = 0; j < 2; ++j) {
                int col = n0 + j * 16 + l15;
                float bval = bq[col];
#pragma unroll
                for (int r = 0; r < 4; ++r)
                    q_bf[(size_t)(i * 16 + crow + r) * NH + col] = f2b((acc[i][j][r] + bval) * SCALE);
            }
    }
}

// ---------------------------------------------------------------------------
// vwtn_scores: t<256: VWt2 tiles (128x128). t>=256 (64 blocks): scores.
__global__ void __launch_bounds__(256, 2)
vwtn_scores(const short* __restrict__ V_bf,
            const short* __restrict__ Wo_bf,
            const short* __restrict__ q_bf,
            const short* __restrict__ K_bf,
            short* __restrict__ VWt,
            short* __restrict__ S_bf) {
    __shared__ short Alds[128 * 64];
    __shared__ short Blds[128 * 64];
    int t = blockIdx.x;
    int tid = threadIdx.x, lane = tid & 63, wid = tid >> 6;
    int l15 = lane & 15;
    int crow = (lane >> 4) * 4;

    if (t < 256) {
        int l = swz8(t, 32); // bh*16 + mt*4 + nt
        int bh = l >> 4, mt = (l >> 2) & 3, nt = l & 3;
        int b = bh >> 1, h = bh & 1;

        const short* Ag = Wo_bf + (size_t)(mt * 128) * NH + h * DH;
        const short* Bg = V_bf + (size_t)(b * SL + nt * 128) * NH + h * DH;

        f32x4 acc[4][4];
#pragma unroll
        for (int i = 0; i < 4; ++i)
#pragma unroll
            for (int j = 0; j < 4; ++j) acc[i][j] = (f32x4)0.f;

        m97_core128(Ag, NH, Bg, NH, DH, Alds, Blds, wid, lane, acc);

        int wm = wid >> 1, wn = wid & 1;
        short* dst = VWt + (size_t)b * NH * 1024 + h * 512;
#pragma unroll
        for (int i = 0; i < 4; ++i)
#pragma unroll
            for (int j = 0; j < 4; ++j) {
                int col = nt * 128 + wn * 64 + j * 16 + l15;     // s
                int row0 = mt * 128 + wm * 64 + i * 16 + crow;   // o
#pragma unroll
                for (int r = 0; r < 4; ++r)
                    dst[(size_t)(row0 + r) * 1024 + col] = f2b(acc[i][j][r]);
            }
    } else {
        // scores: S_bf[b][h][e][s] = EXP(q . K). 64 blocks (register path).
        int l = swz8(t - 256, 8); // b*8 + h*4 + st
        int b = l >> 3, h = (l >> 2) & 1, st = l & 3;
        int n0 = st * 128 + wid * 32;
        int kb = (lane >> 4) * 8;

        f32x4 acc[4][2];
#pragma unroll
        for (int i = 0; i < 4; ++i)
#pragma unroll
            for (int j = 0; j < 2; ++j) acc[i][j] = (f32x4)0.f;

        const short* Aq = q_bf + (size_t)l15 * NH + h * DH + kb;
        const short* Bk = K_bf + ((size_t)b * SL + n0 + l15) * NH + h * DH + kb;

        short8 a0[4], a1[4];
        short8 b0[2], b1[2];
        ldg4(a0, Aq, 0, NH);
        ldg2(b0, Bk, 0, NH);
#pragma unroll
        for (int p = 0; p < 4; ++p) {
            int k1 = p * 64 + 32;
            ldg4(a1, Aq, k1, NH);
            ldg2(b1, Bk, k1, NH);
            mm42(acc, a0, b0);
            if (p < 3) {
                ldg4(a0, Aq, k1 + 32, NH);
                ldg2(b0, Bk, k1 + 32, NH);
            }
            mm42(acc, a1, b1);
        }

#pragma unroll
        for (int i = 0; i < 4; ++i)
#pragma unroll
            for (int j = 0; j < 2; ++j) {
                int col = n0 + j * 16 + l15;
#pragma unroll
                for (int r = 0; r < 4; ++r) {
                    int row = i * 16 + crow + r;
                    S_bf[(((size_t)(b * HEADS + h)) * NE + row) * SL + col] = f2b(__expf(acc[i][j][r]));
                }
            }
    }
}

// ---------------------------------------------------------------------------
// pnorm: P[(b*16+ent)*64+e][h*512+s] = mask ? expS*inv : 0. grid 256.
__global__ void __launch_bounds__(256, 4)
pnorm_kernel(const short* __restrict__ S_bf,
             const void* __restrict__ ents,
             const int* __restrict__ flag,
             short* __restrict__ P) {
    int l = swz8(blockIdx.x, 32); // b*32 + ent*2 + eh
    int b = l >> 5, ent = (l >> 1) & 15, eh = l & 1;
    int tid = threadIdx.x, lane = tid & 63, wid = tid >> 6;

    unsigned att8 = 0;
    {
        size_t mbase = ((size_t)b * EN + ent) * SL + lane * 8;
        if (flag[0]) {
            const int* p = (const int*)ents;
#pragma unroll
            for (int j = 0; j < 8; ++j)
                if (p[mbase + j]) att8 |= 1u << j;
        } else {
            const unsigned char* p = (const unsigned char*)ents;
#pragma unroll
            for (int j = 0; j < 8; ++j)
                if (p[mbase + j]) att8 |= 1u << j;
        }
    }

    for (int it = 0; it < 8; ++it) {
        int e = eh * 32 + wid * 8 + it;
        const short* s0p = S_bf + (((size_t)(b * HEADS + 0)) * NE + e) * SL + lane * 8;
        const short* s1p = S_bf + (((size_t)(b * HEADS + 1)) * NE + e) * SL + lane * 8;
        short8 v0 = *(const short8*)s0p;
        short8 v1 = *(const short8*)s1p;
        float f0[8], f1[8], sum0 = 0.f, sum1 = 0.f;
#pragma unroll
        for (int j = 0; j < 8; ++j) {
            f0[j] = (att8 >> j & 1) ? b2f(v0[j]) : 0.f;
            f1[j] = (att8 >> j & 1) ? b2f(v1[j]) : 0.f;
            sum0 += f0[j];
            sum1 += f1[j];
        }
#pragma unroll
        for (int off = 32; off; off >>= 1) {
            sum0 += __shfl_xor(sum0, off);
            sum1 += __shfl_xor(sum1, off);
        }
        float iv0 = 1.f / sum0, iv1 = 1.f / sum1;
        short8 o0, o1;
#pragma unroll
        for (int j = 0; j < 8; ++j) {
            o0[j] = f2b(f0[j] * iv0);
            o1[j] = f2b(f1[j] * iv1);
        }
        short* prow = P + ((size_t)(b * EN + ent) * NE + e) * 1024;
        *(short8*)(prow + lane * 8) = o0;
        *(short8*)(prow + 512 + lane * 8) = o1;
    }
}

// ---------------------------------------------------------------------------
// outg: out = P @ VWt2^T + bo. M=8192, N=512, K=1024. 128x128 tiles, grid 256.
__global__ void __launch_bounds__(256, 2)
outg(const short* __restrict__ P,
     const short* __restrict__ VWt,
     const float* __restrict__ bo,
     float* __restrict__ out) {
    __shared__ short Alds[128 * 64];
    __shared__ short Blds[128 * 64];
    int l = swz8(blockIdx.x, 32); // b*32 + mt*4 + nt
    int b = l >> 5, mt = (l >> 2) & 7, nt = l & 3;
    int tid = threadIdx.x, lane = tid & 63, wid = tid >> 6;
    int l15 = lane & 15;
    int crow = (lane >> 4) * 4;

    const short* Ag = P + ((size_t)b * 1024 + mt * 128) * 1024;
    const short* Bg = VWt + ((size_t)b * NH + nt * 128) * 1024;

    f32x4 acc[4][4];
#pragma unroll
    for (int i = 0; i < 4; ++i)
#pragma unroll
        for (int j = 0; j < 4; ++j) acc[i][j] = (f32x4)0.f;

    m97_core128(Ag, 1024, Bg, 1024, 1024, Alds, Blds, wid, lane, acc);

    int wm = wid >> 1, wn = wid & 1;
    int gr0 = b * 1024 + mt * 128 + wm * 64;
#pragma unroll
    for (int i = 0; i < 4; ++i)
#pragma unroll
        for (int j = 0; j < 4; ++j) {
            int col = nt * 128 + wn * 64 + j * 16 + l15;
            float bval = bo[col];
#pragma unroll
            for (int r = 0; r < 4; ++r) {
                int row = gr0 + i * 16 + crow + r;
                out[(size_t)row * NH + col] = acc[i][j][r] + bval;
            }
        }
}

// ---------------------------------------------------------------------------
extern "C" void kernel_launch(void* const* d_in, const int* in_sizes, int n_in,
                              void* d_out, int out_size, void* d_ws, size_t ws_size,
                              hipStream_t stream) {
    const float* toks = (const float*)d_in[0];
    const void* ents = d_in[1];
    const float* evs = (const float*)d_in[2];
    const float* Wq = (const float*)d_in[6];
    const float* Wk = (const float*)d_in[7];
    const float* Wv = (const float*)d_in[8];
    const float* bq = (const float*)d_in[9];
    const float* bk = (const float*)d_in[10];
    const float* bv = (const float*)d_in[11];
    const float* Wo = (const float*)d_in[12];
    const float* bo = (const float*)d_in[13];

    char* ws = (char*)d_ws;
    short* toks_bf = (short*)(ws + WS_TOKS);
    short* K_bf = (short*)(ws + WS_K);
    short* V_bf = (short*)(ws + WS_V);
    short* S_bf = (short*)(ws + WS_S);
    short* Wk_bf = (short*)(ws + WS_WK);
    short* Wv_bf = (short*)(ws + WS_WV);
    short* Wo_bf = (short*)(ws + WS_WO);
    short* Wq_bf = (short*)(ws + WS_WQ);
    short* ev_bf = (short*)(ws + WS_EV);
    short* q_bf = (short*)(ws + WS_Q);
    int* flag = (int*)(ws + WS_FLAG);
    short* VWt = (short*)(ws + WS_VW);
    short* P = (short*)(ws + WS_P);

    prep_kernel<<<CH_TOTAL / 256 + 1, 256, 0, stream>>>(
        toks, Wk, Wv, Wo, Wq, evs, (const unsigned char*)ents,
        toks_bf, Wk_bf, Wv_bf, Wo_bf, Wq_bf, ev_bf, flag);
    projn<<<260, 256, 0, stream>>>(toks_bf, Wk_bf, Wv_bf, ev_bf, Wq_bf,
                                   bk, bv, bq, K_bf, V_bf, q_bf);
    vwtn_scores<<<320, 256, 0, stream>>>(V_bf, Wo_bf, q_bf, K_bf, VWt, S_bf);
    pnorm_kernel<<<256, 256, 0, stream>>>(S_bf, ents, flag, P);
    outg<<<256, 256, 0, stream>>>(P, VWt, bo, (float*)d_out);
}

// Round 21
// 66.056 us; speedup vs baseline: 1.6839x; 1.0211x over previous
//
#include <hip/hip_runtime.h>

// EntityAttention — round 21: R20 base (67.5 µs) + T3-minimum 2-phase
// schedule in the GEMM core: double-buffered LDS, stage(next) issued BEFORE
// compute(cur), single barrier per K-step. Only the schedule changes.
// NB=8 SL=512 NH=512 EN=16 NE=64 HEADS=2 DH=256.

#define NB 8
#define SL 512
#define NH 512
#define EN 16
#define NE 64
#define HEADS 2
#define DH 256
#define SCALE 0.0625f

typedef __attribute__((ext_vector_type(8))) short short8;
typedef __attribute__((ext_vector_type(4))) short short4v;
typedef __attribute__((ext_vector_type(4))) float f32x4;

#define MFMA16(a, b, c) __builtin_amdgcn_mfma_f32_16x16x32_bf16(a, b, c, 0, 0, 0)

__device__ __forceinline__ short f2b(float f) {
    unsigned u = __builtin_bit_cast(unsigned, f);
    u += 0x7fffu + ((u >> 16) & 1u);
    return (short)(u >> 16);
}
__device__ __forceinline__ float b2f(short s) {
    return __builtin_bit_cast(float, ((unsigned)(unsigned short)s) << 16);
}
__device__ __forceinline__ int swz8(int hw, int chunk) {
    return (hw & 7) * chunk + (hw >> 3);
}

// async global->LDS, 16B per lane; HW writes lane l at ldsbase + l*16.
__device__ __forceinline__ void gload16(const short* g, short* l) {
    __builtin_amdgcn_global_load_lds(
        (const __attribute__((address_space(1))) unsigned int*)g,
        (__attribute__((address_space(3))) unsigned int*)l, 16, 0, 0);
}

__device__ __forceinline__ void ldg4(short8 (&d)[4], const short* p, int k, int stride) {
#pragma unroll
    for (int j = 0; j < 4; ++j) d[j] = *(const short8*)(p + (size_t)j * 16 * stride + k);
}
__device__ __forceinline__ void ldg2(short8 (&d)[2], const short* p, int k, int stride) {
#pragma unroll
    for (int j = 0; j < 2; ++j) d[j] = *(const short8*)(p + (size_t)j * 16 * stride + k);
}
__device__ __forceinline__ void mm42(f32x4 (&acc)[4][2], const short8 (&a)[4], const short8 (&bb)[2]) {
#pragma unroll
    for (int i = 0; i < 4; ++i)
#pragma unroll
        for (int j = 0; j < 2; ++j) acc[i][j] = MFMA16(a[i], bb[j], acc[i][j]);
}
__device__ __forceinline__ void mm44(f32x4 (&acc)[4][4], const short8 (&a)[4], const short8 (&bb)[4]) {
#pragma unroll
    for (int i = 0; i < 4; ++i)
#pragma unroll
        for (int j = 0; j < 4; ++j) acc[i][j] = MFMA16(a[i], bb[j], acc[i][j]);
}

// ---- ws byte offsets (aliasing-free layout from R19) -----------------------
#define WS_TOKS 0u
#define WS_K (4u << 20)
#define WS_V (8u << 20)
#define WS_S (20u << 20)
#define WS_WK (22u << 20)
#define WS_WV (WS_WK + (512u << 10))
#define WS_WO (WS_WV + (512u << 10))
#define WS_WQ (WS_WO + (512u << 10))
#define WS_EV (WS_WQ + (512u << 10))
#define WS_Q (WS_EV + (64u << 10))
#define WS_FLAG (WS_Q + (64u << 10))
#define WS_VW (32u << 20)  /* VWt2[b][o][h*512+s]: 32..40 MB */
#define WS_P (40u << 20)   /* P[slot][e][1024]: 40..56.8 MB */

#define CH_TOKS (NB * SL * NH / 4)
#define CH_W (NH * NH / 4)
#define CH_EV (NE * NH / 4)
#define CH_TOTAL (CH_TOKS + 4 * CH_W + CH_EV)

// ---------------------------------------------------------------------------
__global__ void prep_kernel(const float* __restrict__ toks, const float* __restrict__ Wk,
                            const float* __restrict__ Wv, const float* __restrict__ Wo,
                            const float* __restrict__ Wq, const float* __restrict__ ev,
                            const unsigned char* __restrict__ ents,
                            short* __restrict__ toks_bf, short* __restrict__ Wk_bf,
                            short* __restrict__ Wv_bf, short* __restrict__ Wo_bf,
                            short* __restrict__ Wq_bf, short* __restrict__ ev_bf,
                            int* __restrict__ flag) {
    __shared__ int red[256];
    int idx = blockIdx.x * 256 + threadIdx.x;
    if (idx < CH_TOTAL) {
        const float* src;
        short* dst;
        int off = idx;
        if (idx < CH_TOKS) { src = toks; dst = toks_bf; }
        else if (idx < CH_TOKS + CH_W) { src = Wk; dst = Wk_bf; off -= CH_TOKS; }
        else if (idx < CH_TOKS + 2 * CH_W) { src = Wv; dst = Wv_bf; off -= CH_TOKS + CH_W; }
        else if (idx < CH_TOKS + 3 * CH_W) { src = Wo; dst = Wo_bf; off -= CH_TOKS + 2 * CH_W; }
        else if (idx < CH_TOKS + 4 * CH_W) { src = Wq; dst = Wq_bf; off -= CH_TOKS + 3 * CH_W; }
        else { src = ev; dst = ev_bf; off -= CH_TOKS + 4 * CH_W; }
        f32x4 v = ((const f32x4*)src)[off];
        short4v o;
#pragma unroll
        for (int j = 0; j < 4; ++j) o[j] = f2b(v[j]);
        ((short4v*)dst)[off] = o;
    }
    if (blockIdx.x == gridDim.x - 1) {
        int tid = threadIdx.x;
        int cnt = 0;
        for (int j = 0; j < 16; ++j) {
            int off = tid * 16 + j;
            if ((off & 3) != 0 && ents[off] != 0) cnt++;
        }
        red[tid] = cnt;
        __syncthreads();
        for (int s = 128; s > 0; s >>= 1) {
            if (tid < s) red[tid] += red[tid + s];
            __syncthreads();
        }
        if (tid == 0) flag[0] = (red[0] == 0) ? 1 : 0;
    }
}

// ---------------------------------------------------------------------------
// m97 core, 128x128 tile, DOUBLE-BUFFERED 2-phase: stage(k+1 -> other buf)
// issued before compute(k); one barrier per step (drains prefetch + guards
// buffer reuse). Alds/Blds are 2 x 8192 shorts (16 KB x 2 each).
__device__ __forceinline__ void m97_core128(
    const short* __restrict__ Ag, int lda,
    const short* __restrict__ Bg, int ldb, int K,
    short* Alds, short* Blds, int wid, int lane, f32x4 (&acc)[4][4]) {
    int wm = wid >> 1, wn = wid & 1;
    int l15 = lane & 15;
    int rl = lane >> 3;             // 0..7: row within an 8-row chunk
    int xb = (lane & 7) << 4;       // byte 0..112 within the 128B row
    int kx = (xb ^ (rl << 4)) >> 1; // pre-swizzled source element offset

    const short* aG0 = Ag + (size_t)(wid * 8 + rl) * lda + kx;
    const short* bG0 = Bg + (size_t)(wid * 8 + rl) * ldb + kx;
    size_t aCs = (size_t)32 * lda;  // chunk stride = 32 rows
    size_t bCs = (size_t)32 * ldb;

    auto stage = [&](int k0, int buf) {
        short* aL0 = Alds + buf * 8192 + wid * 512;
        short* bL0 = Blds + buf * 8192 + wid * 512;
#pragma unroll
        for (int c = 0; c < 4; ++c) {
            gload16(aG0 + c * aCs + k0, aL0 + c * 2048);
            gload16(bG0 + c * bCs + k0, bL0 + c * 2048);
        }
    };

    stage(0, 0);
    __syncthreads(); // buf0 ready
    int buf = 0;
    for (int k0 = 0; k0 < K; k0 += 64, buf ^= 1) {
        if (k0 + 64 < K) stage(k0 + 64, buf ^ 1); // prefetch under compute
        const char* Ab = (const char*)(Alds + buf * 8192);
        const char* Bb = (const char*)(Blds + buf * 8192);
#pragma unroll
        for (int kk = 0; kk < 2; ++kk) {
            int x = kk * 64 + ((lane >> 4) << 4);
            short8 af[4], bf_[4];
#pragma unroll
            for (int i = 0; i < 4; ++i) {
                int row = wm * 64 + i * 16 + l15;
                af[i] = *(const short8*)(Ab + row * 128 + (x ^ ((row & 7) << 4)));
            }
#pragma unroll
            for (int j = 0; j < 4; ++j) {
                int row = wn * 64 + j * 16 + l15;
                bf_[j] = *(const short8*)(Bb + row * 128 + (x ^ ((row & 7) << 4)));
            }
            mm44(acc, af, bf_);
        }
        __syncthreads(); // prefetch drained + all reads of buf done
    }
}

// ---------------------------------------------------------------------------
// projn: t<256: K/V projection (128x128 tiles); t>=256 (4 blocks): q (old).
__global__ void __launch_bounds__(256, 2)
projn(const short* __restrict__ toks_bf,
      const short* __restrict__ Wk_bf,
      const short* __restrict__ Wv_bf,
      const short* __restrict__ ev_bf,
      const short* __restrict__ Wq_bf,
      const float* __restrict__ bk, const float* __restrict__ bv,
      const float* __restrict__ bq,
      short* __restrict__ K_bf, short* __restrict__ V_bf,
      short* __restrict__ q_bf) {
    __shared__ short Alds[2 * 128 * 64];
    __shared__ short Blds[2 * 128 * 64];
    int t = blockIdx.x;
    int tid = threadIdx.x, lane = tid & 63, wid = tid >> 6;
    int l15 = lane & 15;
    int crow = (lane >> 4) * 4;

    if (t < 256) {
        int l = swz8(t, 32); // b*32 + kind*16 + mt*4 + nt
        int b = l >> 5, kind = (l >> 4) & 1, mt = (l >> 2) & 3, nt = l & 3;
        const short* Ag = toks_bf + (size_t)(b * SL + mt * 128) * NH;
        const short* Bg = (kind ? Wv_bf : Wk_bf) + (size_t)(nt * 128) * NH;
        const float* bias = kind ? bv : bk;
        short* dst = kind ? V_bf : K_bf;

        f32x4 acc[4][4];
#pragma unroll
        for (int i = 0; i < 4; ++i)
#pragma unroll
            for (int j = 0; j < 4; ++j) acc[i][j] = (f32x4)0.f;

        m97_core128(Ag, NH, Bg, NH, NH, Alds, Blds, wid, lane, acc);

        int wm = wid >> 1, wn = wid & 1;
#pragma unroll
        for (int i = 0; i < 4; ++i)
#pragma unroll
            for (int j = 0; j < 4; ++j) {
                int col = nt * 128 + wn * 64 + j * 16 + l15;
                float bval = bias[col];
                int row0 = b * SL + mt * 128 + wm * 64 + i * 16 + crow;
#pragma unroll
                for (int r = 0; r < 4; ++r)
                    dst[(size_t)(row0 + r) * NH + col] = f2b(acc[i][j][r] + bval);
            }
    } else {
        // q projection: M=64, N=512 over 4 blocks; wave = 64e x 32cols.
        int tq = t - 256;
        int kb = (lane >> 4) * 8;
        int n0 = tq * 128 + wid * 32;
        const short* A = ev_bf + (size_t)l15 * NH + kb;
        const short* B = Wq_bf + (size_t)(n0 + l15) * NH + kb;

        f32x4 acc[4][2];
#pragma unroll
        for (int i = 0; i < 4; ++i)
#pragma unroll
            for (int j = 0; j < 2; ++j) acc[i][j] = (f32x4)0.f;

        for (int k = 0; k < NH; k += 32) {
            short8 a[4], bb[2];
#pragma unroll
            for (int i = 0; i < 4; ++i) a[i] = *(const short8*)(A + (size_t)i * 16 * NH + k);
#pragma unroll
            for (int j = 0; j < 2; ++j) bb[j] = *(const short8*)(B + (size_t)j * 16 * NH + k);
            mm42(acc, a, bb);
        }

#pragma unroll
        for (int i = 0; i < 4; ++i)
#pragma unroll
            for (int j = 0; j < 2; ++j) {
                int col = n0 + j * 16 + l15;
                float bval = bq[col];
#pragma unroll
                for (int r = 0; r < 4; ++r)
                    q_bf[(size_t)(i * 16 + crow + r) * NH + col] = f2b((acc[i][j][r] + bval) * SCALE);
            }
    }
}

// ---------------------------------------------------------------------------
// vwtn_scores: t<256: VWt2 tiles (128x128). t>=256 (64 blocks): scores.
__global__ void __launch_bounds__(256, 2)
vwtn_scores(const short* __restrict__ V_bf,
            const short* __restrict__ Wo_bf,
            const short* __restrict__ q_bf,
            const short* __restrict__ K_bf,
            short* __restrict__ VWt,
            short* __restrict__ S_bf) {
    __shared__ short Alds[2 * 128 * 64];
    __shared__ short Blds[2 * 128 * 64];
    int t = blockIdx.x;
    int tid = threadIdx.x, lane = tid & 63, wid = tid >> 6;
    int l15 = lane & 15;
    int crow = (lane >> 4) * 4;

    if (t < 256) {
        int l = swz8(t, 32); // bh*16 + mt*4 + nt
        int bh = l >> 4, mt = (l >> 2) & 3, nt = l & 3;
        int b = bh >> 1, h = bh & 1;

        const short* Ag = Wo_bf + (size_t)(mt * 128) * NH + h * DH;
        const short* Bg = V_bf + (size_t)(b * SL + nt * 128) * NH + h * DH;

        f32x4 acc[4][4];
#pragma unroll
        for (int i = 0; i < 4; ++i)
#pragma unroll
            for (int j = 0; j < 4; ++j) acc[i][j] = (f32x4)0.f;

        m97_core128(Ag, NH, Bg, NH, DH, Alds, Blds, wid, lane, acc);

        int wm = wid >> 1, wn = wid & 1;
        short* dst = VWt + (size_t)b * NH * 1024 + h * 512;
#pragma unroll
        for (int i = 0; i < 4; ++i)
#pragma unroll
            for (int j = 0; j < 4; ++j) {
                int col = nt * 128 + wn * 64 + j * 16 + l15;     // s
                int row0 = mt * 128 + wm * 64 + i * 16 + crow;   // o
#pragma unroll
                for (int r = 0; r < 4; ++r)
                    dst[(size_t)(row0 + r) * 1024 + col] = f2b(acc[i][j][r]);
            }
    } else {
        // scores: S_bf[b][h][e][s] = EXP(q . K). 64 blocks (register path).
        int l = swz8(t - 256, 8); // b*8 + h*4 + st
        int b = l >> 3, h = (l >> 2) & 1, st = l & 3;
        int n0 = st * 128 + wid * 32;
        int kb = (lane >> 4) * 8;

        f32x4 acc[4][2];
#pragma unroll
        for (int i = 0; i < 4; ++i)
#pragma unroll
            for (int j = 0; j < 2; ++j) acc[i][j] = (f32x4)0.f;

        const short* Aq = q_bf + (size_t)l15 * NH + h * DH + kb;
        const short* Bk = K_bf + ((size_t)b * SL + n0 + l15) * NH + h * DH + kb;

        short8 a0[4], a1[4];
        short8 b0[2], b1[2];
        ldg4(a0, Aq, 0, NH);
        ldg2(b0, Bk, 0, NH);
#pragma unroll
        for (int p = 0; p < 4; ++p) {
            int k1 = p * 64 + 32;
            ldg4(a1, Aq, k1, NH);
            ldg2(b1, Bk, k1, NH);
            mm42(acc, a0, b0);
            if (p < 3) {
                ldg4(a0, Aq, k1 + 32, NH);
                ldg2(b0, Bk, k1 + 32, NH);
            }
            mm42(acc, a1, b1);
        }

#pragma unroll
        for (int i = 0; i < 4; ++i)
#pragma unroll
            for (int j = 0; j < 2; ++j) {
                int col = n0 + j * 16 + l15;
#pragma unroll
                for (int r = 0; r < 4; ++r) {
                    int row = i * 16 + crow + r;
                    S_bf[(((size_t)(b * HEADS + h)) * NE + row) * SL + col] = f2b(__expf(acc[i][j][r]));
                }
            }
    }
}

// ---------------------------------------------------------------------------
// pnorm: P[(b*16+ent)*64+e][h*512+s] = mask ? expS*inv : 0. grid 256.
__global__ void __launch_bounds__(256, 4)
pnorm_kernel(const short* __restrict__ S_bf,
             const void* __restrict__ ents,
             const int* __restrict__ flag,
             short* __restrict__ P) {
    int l = swz8(blockIdx.x, 32); // b*32 + ent*2 + eh
    int b = l >> 5, ent = (l >> 1) & 15, eh = l & 1;
    int tid = threadIdx.x, lane = tid & 63, wid = tid >> 6;

    unsigned att8 = 0;
    {
        size_t mbase = ((size_t)b * EN + ent) * SL + lane * 8;
        if (flag[0]) {
            const int* p = (const int*)ents;
#pragma unroll
            for (int j = 0; j < 8; ++j)
                if (p[mbase + j]) att8 |= 1u << j;
        } else {
            const unsigned char* p = (const unsigned char*)ents;
#pragma unroll
            for (int j = 0; j < 8; ++j)
                if (p[mbase + j]) att8 |= 1u << j;
        }
    }

    for (int it = 0; it < 8; ++it) {
        int e = eh * 32 + wid * 8 + it;
        const short* s0p = S_bf + (((size_t)(b * HEADS + 0)) * NE + e) * SL + lane * 8;
        const short* s1p = S_bf + (((size_t)(b * HEADS + 1)) * NE + e) * SL + lane * 8;
        short8 v0 = *(const short8*)s0p;
        short8 v1 = *(const short8*)s1p;
        float f0[8], f1[8], sum0 = 0.f, sum1 = 0.f;
#pragma unroll
        for (int j = 0; j < 8; ++j) {
            f0[j] = (att8 >> j & 1) ? b2f(v0[j]) : 0.f;
            f1[j] = (att8 >> j & 1) ? b2f(v1[j]) : 0.f;
            sum0 += f0[j];
            sum1 += f1[j];
        }
#pragma unroll
        for (int off = 32; off; off >>= 1) {
            sum0 += __shfl_xor(sum0, off);
            sum1 += __shfl_xor(sum1, off);
        }
        float iv0 = 1.f / sum0, iv1 = 1.f / sum1;
        short8 o0, o1;
#pragma unroll
        for (int j = 0; j < 8; ++j) {
            o0[j] = f2b(f0[j] * iv0);
            o1[j] = f2b(f1[j] * iv1);
        }
        short* prow = P + ((size_t)(b * EN + ent) * NE + e) * 1024;
        *(short8*)(prow + lane * 8) = o0;
        *(short8*)(prow + 512 + lane * 8) = o1;
    }
}

// ---------------------------------------------------------------------------
// outg: out = P @ VWt2^T + bo. M=8192, N=512, K=1024. 128x128 tiles, grid 256.
__global__ void __launch_bounds__(256, 2)
outg(const short* __restrict__ P,
     const short* __restrict__ VWt,
     const float* __restrict__ bo,
     float* __restrict__ out) {
    __shared__ short Alds[2 * 128 * 64];
    __shared__ short Blds[2 * 128 * 64];
    int l = swz8(blockIdx.x, 32); // b*32 + mt*4 + nt
    int b = l >> 5, mt = (l >> 2) & 7, nt = l & 3;
    int tid = threadIdx.x, lane = tid & 63, wid = tid >> 6;
    int l15 = lane & 15;
    int crow = (lane >> 4) * 4;

    const short* Ag = P + ((size_t)b * 1024 + mt * 128) * 1024;
    const short* Bg = VWt + ((size_t)b * NH + nt * 128) * 1024;

    f32x4 acc[4][4];
#pragma unroll
    for (int i = 0; i < 4; ++i)
#pragma unroll
        for (int j = 0; j < 4; ++j) acc[i][j] = (f32x4)0.f;

    m97_core128(Ag, 1024, Bg, 1024, 1024, Alds, Blds, wid, lane, acc);

    int wm = wid >> 1, wn = wid & 1;
    int gr0 = b * 1024 + mt * 128 + wm * 64;
#pragma unroll
    for (int i = 0; i < 4; ++i)
#pragma unroll
        for (int j = 0; j < 4; ++j) {
            int col = nt * 128 + wn * 64 + j * 16 + l15;
            float bval = bo[col];
#pragma unroll
            for (int r = 0; r < 4; ++r) {
                int row = gr0 + i * 16 + crow + r;
                out[(size_t)row * NH + col] = acc[i][j][r] + bval;
            }
        }
}

// ---------------------------------------------------------------------------
extern "C" void kernel_launch(void* const* d_in, const int* in_sizes, int n_in,
                              void* d_out, int out_size, void* d_ws, size_t ws_size,
                              hipStream_t stream) {
    const float* toks = (const float*)d_in[0];
    const void* ents = d_in[1];
    const float* evs = (const float*)d_in[2];
    const float* Wq = (const float*)d_in[6];
    const float* Wk = (const float*)d_in[7];
    const float* Wv = (const float*)d_in[8];
    const float* bq = (const float*)d_in[9];
    const float* bk = (const float*)d_in[10];
    const float* bv = (const float*)d_in[11];
    const float* Wo = (const float*)d_in[12];
    const float* bo = (const float*)d_in[13];

    char* ws = (char*)d_ws;
    short* toks_bf = (short*)(ws + WS_TOKS);
    short* K_bf = (short*)(ws + WS_K);
    short* V_bf = (short*)(ws + WS_V);
    short* S_bf = (short*)(ws + WS_S);
    short* Wk_bf = (short*)(ws + WS_WK);
    short* Wv_bf = (short*)(ws + WS_WV);
    short* Wo_bf = (short*)(ws + WS_WO);
    short* Wq_bf = (short*)(ws + WS_WQ);
    short* ev_bf = (short*)(ws + WS_EV);
    short* q_bf = (short*)(ws + WS_Q);
    int* flag = (int*)(ws + WS_FLAG);
    short* VWt = (short*)(ws + WS_VW);
    short* P = (short*)(ws + WS_P);

    prep_kernel<<<CH_TOTAL / 256 + 1, 256, 0, stream>>>(
        toks, Wk, Wv, Wo, Wq, evs, (const unsigned char*)ents,
        toks_bf, Wk_bf, Wv_bf, Wo_bf, Wq_bf, ev_bf, flag);
    projn<<<260, 256, 0, stream>>>(toks_bf, Wk_bf, Wv_bf, ev_bf, Wq_bf,
                                   bk, bv, bq, K_bf, V_bf, q_bf);
    vwtn_scores<<<320, 256, 0, stream>>>(V_bf, Wo_bf, q_bf, K_bf, VWt, S_bf);
    pnorm_kernel<<<256, 256, 0, stream>>>(S_bf, ents, flag, P);
    outg<<<256, 256, 0, stream>>>(P, VWt, bo, (float*)d_out);
}

// Round 22
// 62.881 us; speedup vs baseline: 1.7690x; 1.0505x over previous
//
#include <hip/hip_runtime.h>

// EntityAttention — round 22: R21 + T4 counted-vmcnt pipeline. The dbuf
// prefetch was being drained by __syncthreads' implicit vmcnt(0); replaced
// with raw s_barrier + s_waitcnt vmcnt(8) so next-buffer loads stay in
// flight across the barrier. Only the core's sync schedule changes.
// NB=8 SL=512 NH=512 EN=16 NE=64 HEADS=2 DH=256.

#define NB 8
#define SL 512
#define NH 512
#define EN 16
#define NE 64
#define HEADS 2
#define DH 256
#define SCALE 0.0625f

typedef __attribute__((ext_vector_type(8))) short short8;
typedef __attribute__((ext_vector_type(4))) short short4v;
typedef __attribute__((ext_vector_type(4))) float f32x4;

#define MFMA16(a, b, c) __builtin_amdgcn_mfma_f32_16x16x32_bf16(a, b, c, 0, 0, 0)

__device__ __forceinline__ short f2b(float f) {
    unsigned u = __builtin_bit_cast(unsigned, f);
    u += 0x7fffu + ((u >> 16) & 1u);
    return (short)(u >> 16);
}
__device__ __forceinline__ float b2f(short s) {
    return __builtin_bit_cast(float, ((unsigned)(unsigned short)s) << 16);
}
__device__ __forceinline__ int swz8(int hw, int chunk) {
    return (hw & 7) * chunk + (hw >> 3);
}

// async global->LDS, 16B per lane; HW writes lane l at ldsbase + l*16.
__device__ __forceinline__ void gload16(const short* g, short* l) {
    __builtin_amdgcn_global_load_lds(
        (const __attribute__((address_space(1))) unsigned int*)g,
        (__attribute__((address_space(3))) unsigned int*)l, 16, 0, 0);
}

__device__ __forceinline__ void ldg4(short8 (&d)[4], const short* p, int k, int stride) {
#pragma unroll
    for (int j = 0; j < 4; ++j) d[j] = *(const short8*)(p + (size_t)j * 16 * stride + k);
}
__device__ __forceinline__ void ldg2(short8 (&d)[2], const short* p, int k, int stride) {
#pragma unroll
    for (int j = 0; j < 2; ++j) d[j] = *(const short8*)(p + (size_t)j * 16 * stride + k);
}
__device__ __forceinline__ void mm42(f32x4 (&acc)[4][2], const short8 (&a)[4], const short8 (&bb)[2]) {
#pragma unroll
    for (int i = 0; i < 4; ++i)
#pragma unroll
        for (int j = 0; j < 2; ++j) acc[i][j] = MFMA16(a[i], bb[j], acc[i][j]);
}
__device__ __forceinline__ void mm44(f32x4 (&acc)[4][4], const short8 (&a)[4], const short8 (&bb)[4]) {
#pragma unroll
    for (int i = 0; i < 4; ++i)
#pragma unroll
        for (int j = 0; j < 4; ++j) acc[i][j] = MFMA16(a[i], bb[j], acc[i][j]);
}

// ---- ws byte offsets (aliasing-free layout from R19) -----------------------
#define WS_TOKS 0u
#define WS_K (4u << 20)
#define WS_V (8u << 20)
#define WS_S (20u << 20)
#define WS_WK (22u << 20)
#define WS_WV (WS_WK + (512u << 10))
#define WS_WO (WS_WV + (512u << 10))
#define WS_WQ (WS_WO + (512u << 10))
#define WS_EV (WS_WQ + (512u << 10))
#define WS_Q (WS_EV + (64u << 10))
#define WS_FLAG (WS_Q + (64u << 10))
#define WS_VW (32u << 20)  /* VWt2[b][o][h*512+s]: 32..40 MB */
#define WS_P (40u << 20)   /* P[slot][e][1024]: 40..56.8 MB */

#define CH_TOKS (NB * SL * NH / 4)
#define CH_W (NH * NH / 4)
#define CH_EV (NE * NH / 4)
#define CH_TOTAL (CH_TOKS + 4 * CH_W + CH_EV)

// ---------------------------------------------------------------------------
__global__ void prep_kernel(const float* __restrict__ toks, const float* __restrict__ Wk,
                            const float* __restrict__ Wv, const float* __restrict__ Wo,
                            const float* __restrict__ Wq, const float* __restrict__ ev,
                            const unsigned char* __restrict__ ents,
                            short* __restrict__ toks_bf, short* __restrict__ Wk_bf,
                            short* __restrict__ Wv_bf, short* __restrict__ Wo_bf,
                            short* __restrict__ Wq_bf, short* __restrict__ ev_bf,
                            int* __restrict__ flag) {
    __shared__ int red[256];
    int idx = blockIdx.x * 256 + threadIdx.x;
    if (idx < CH_TOTAL) {
        const float* src;
        short* dst;
        int off = idx;
        if (idx < CH_TOKS) { src = toks; dst = toks_bf; }
        else if (idx < CH_TOKS + CH_W) { src = Wk; dst = Wk_bf; off -= CH_TOKS; }
        else if (idx < CH_TOKS + 2 * CH_W) { src = Wv; dst = Wv_bf; off -= CH_TOKS + CH_W; }
        else if (idx < CH_TOKS + 3 * CH_W) { src = Wo; dst = Wo_bf; off -= CH_TOKS + 2 * CH_W; }
        else if (idx < CH_TOKS + 4 * CH_W) { src = Wq; dst = Wq_bf; off -= CH_TOKS + 3 * CH_W; }
        else { src = ev; dst = ev_bf; off -= CH_TOKS + 4 * CH_W; }
        f32x4 v = ((const f32x4*)src)[off];
        short4v o;
#pragma unroll
        for (int j = 0; j < 4; ++j) o[j] = f2b(v[j]);
        ((short4v*)dst)[off] = o;
    }
    if (blockIdx.x == gridDim.x - 1) {
        int tid = threadIdx.x;
        int cnt = 0;
        for (int j = 0; j < 16; ++j) {
            int off = tid * 16 + j;
            if ((off & 3) != 0 && ents[off] != 0) cnt++;
        }
        red[tid] = cnt;
        __syncthreads();
        for (int s = 128; s > 0; s >>= 1) {
            if (tid < s) red[tid] += red[tid + s];
            __syncthreads();
        }
        if (tid == 0) flag[0] = (red[0] == 0) ? 1 : 0;
    }
}

// ---------------------------------------------------------------------------
// m97 core, 128x128 tile, dbuf + COUNTED vmcnt: per step
//   compute(buf) -> s_barrier -> stage(k+128 -> buf) -> vmcnt(8) -> s_barrier
// The 8 loads just issued stay in flight across the compute of the next step.
__device__ __forceinline__ void m97_core128(
    const short* __restrict__ Ag, int lda,
    const short* __restrict__ Bg, int ldb, int K,
    short* Alds, short* Blds, int wid, int lane, f32x4 (&acc)[4][4]) {
    int wm = wid >> 1, wn = wid & 1;
    int l15 = lane & 15;
    int rl = lane >> 3;
    int xb = (lane & 7) << 4;
    int kx = (xb ^ (rl << 4)) >> 1;

    const short* aG0 = Ag + (size_t)(wid * 8 + rl) * lda + kx;
    const short* bG0 = Bg + (size_t)(wid * 8 + rl) * ldb + kx;
    size_t aCs = (size_t)32 * lda;
    size_t bCs = (size_t)32 * ldb;

    auto stage = [&](int k0, int buf) {
        short* aL0 = Alds + buf * 8192 + wid * 512;
        short* bL0 = Blds + buf * 8192 + wid * 512;
#pragma unroll
        for (int c = 0; c < 4; ++c) {
            gload16(aG0 + c * aCs + k0, aL0 + c * 2048);
            gload16(bG0 + c * bCs + k0, bL0 + c * 2048);
        }
    };
    auto compute = [&](int buf) {
        const char* Ab = (const char*)(Alds + buf * 8192);
        const char* Bb = (const char*)(Blds + buf * 8192);
#pragma unroll
        for (int kk = 0; kk < 2; ++kk) {
            int x = kk * 64 + ((lane >> 4) << 4);
            short8 af[4], bf_[4];
#pragma unroll
            for (int i = 0; i < 4; ++i) {
                int row = wm * 64 + i * 16 + l15;
                af[i] = *(const short8*)(Ab + row * 128 + (x ^ ((row & 7) << 4)));
            }
#pragma unroll
            for (int j = 0; j < 4; ++j) {
                int row = wn * 64 + j * 16 + l15;
                bf_[j] = *(const short8*)(Bb + row * 128 + (x ^ ((row & 7) << 4)));
            }
            mm44(acc, af, bf_);
        }
    };

    int nsteps = K >> 6; // K/64, always >= 4 here
    stage(0, 0);
    stage(64, 1);
    asm volatile("s_waitcnt vmcnt(8)" ::: "memory"); // buf0's 8 loads done
    __builtin_amdgcn_sched_barrier(0);
    __builtin_amdgcn_s_barrier();

    int buf = 0;
    for (int s = 0; s < nsteps; ++s, buf ^= 1) {
        compute(buf);
        if (s + 1 < nsteps) {
            __builtin_amdgcn_s_barrier(); // all reads of buf done
            if (s + 2 < nsteps) {
                stage((s + 2) * 64, buf);
                asm volatile("s_waitcnt vmcnt(8)" ::: "memory"); // next buf ready
            } else {
                asm volatile("s_waitcnt vmcnt(0)" ::: "memory");
            }
            __builtin_amdgcn_sched_barrier(0);
            __builtin_amdgcn_s_barrier(); // all waves see next buf staged
        }
    }
}

// ---------------------------------------------------------------------------
// projn: t<256: K/V projection (128x128 tiles); t>=256 (4 blocks): q (old).
__global__ void __launch_bounds__(256, 2)
projn(const short* __restrict__ toks_bf,
      const short* __restrict__ Wk_bf,
      const short* __restrict__ Wv_bf,
      const short* __restrict__ ev_bf,
      const short* __restrict__ Wq_bf,
      const float* __restrict__ bk, const float* __restrict__ bv,
      const float* __restrict__ bq,
      short* __restrict__ K_bf, short* __restrict__ V_bf,
      short* __restrict__ q_bf) {
    __shared__ short Alds[2 * 128 * 64];
    __shared__ short Blds[2 * 128 * 64];
    int t = blockIdx.x;
    int tid = threadIdx.x, lane = tid & 63, wid = tid >> 6;
    int l15 = lane & 15;
    int crow = (lane >> 4) * 4;

    if (t < 256) {
        int l = swz8(t, 32); // b*32 + kind*16 + mt*4 + nt
        int b = l >> 5, kind = (l >> 4) & 1, mt = (l >> 2) & 3, nt = l & 3;
        const short* Ag = toks_bf + (size_t)(b * SL + mt * 128) * NH;
        const short* Bg = (kind ? Wv_bf : Wk_bf) + (size_t)(nt * 128) * NH;
        const float* bias = kind ? bv : bk;
        short* dst = kind ? V_bf : K_bf;

        f32x4 acc[4][4];
#pragma unroll
        for (int i = 0; i < 4; ++i)
#pragma unroll
            for (int j = 0; j < 4; ++j) acc[i][j] = (f32x4)0.f;

        m97_core128(Ag, NH, Bg, NH, NH, Alds, Blds, wid, lane, acc);

        int wm = wid >> 1, wn = wid & 1;
#pragma unroll
        for (int i = 0; i < 4; ++i)
#pragma unroll
            for (int j = 0; j < 4; ++j) {
                int col = nt * 128 + wn * 64 + j * 16 + l15;
                float bval = bias[col];
                int row0 = b * SL + mt * 128 + wm * 64 + i * 16 + crow;
#pragma unroll
                for (int r = 0; r < 4; ++r)
                    dst[(size_t)(row0 + r) * NH + col] = f2b(acc[i][j][r] + bval);
            }
    } else {
        // q projection: M=64, N=512 over 4 blocks; wave = 64e x 32cols.
        int tq = t - 256;
        int kb = (lane >> 4) * 8;
        int n0 = tq * 128 + wid * 32;
        const short* A = ev_bf + (size_t)l15 * NH + kb;
        const short* B = Wq_bf + (size_t)(n0 + l15) * NH + kb;

        f32x4 acc[4][2];
#pragma unroll
        for (int i = 0; i < 4; ++i)
#pragma unroll
            for (int j = 0; j < 2; ++j) acc[i][j] = (f32x4)0.f;

        for (int k = 0; k < NH; k += 32) {
            short8 a[4], bb[2];
#pragma unroll
            for (int i = 0; i < 4; ++i) a[i] = *(const short8*)(A + (size_t)i * 16 * NH + k);
#pragma unroll
            for (int j = 0; j < 2; ++j) bb[j] = *(const short8*)(B + (size_t)j * 16 * NH + k);
            mm42(acc, a, bb);
        }

#pragma unroll
        for (int i = 0; i < 4; ++i)
#pragma unroll
            for (int j = 0; j < 2; ++j) {
                int col = n0 + j * 16 + l15;
                float bval = bq[col];
#pragma unroll
                for (int r = 0; r < 4; ++r)
                    q_bf[(size_t)(i * 16 + crow + r) * NH + col] = f2b((acc[i][j][r] + bval) * SCALE);
            }
    }
}

// ---------------------------------------------------------------------------
// vwtn_scores: t<256: VWt2 tiles (128x128). t>=256 (64 blocks): scores.
__global__ void __launch_bounds__(256, 2)
vwtn_scores(const short* __restrict__ V_bf,
            const short* __restrict__ Wo_bf,
            const short* __restrict__ q_bf,
            const short* __restrict__ K_bf,
            short* __restrict__ VWt,
            short* __restrict__ S_bf) {
    __shared__ short Alds[2 * 128 * 64];
    __shared__ short Blds[2 * 128 * 64];
    int t = blockIdx.x;
    int tid = threadIdx.x, lane = tid & 63, wid = tid >> 6;
    int l15 = lane & 15;
    int crow = (lane >> 4) * 4;

    if (t < 256) {
        int l = swz8(t, 32); // bh*16 + mt*4 + nt
        int bh = l >> 4, mt = (l >> 2) & 3, nt = l & 3;
        int b = bh >> 1, h = bh & 1;

        const short* Ag = Wo_bf + (size_t)(mt * 128) * NH + h * DH;
        const short* Bg = V_bf + (size_t)(b * SL + nt * 128) * NH + h * DH;

        f32x4 acc[4][4];
#pragma unroll
        for (int i = 0; i < 4; ++i)
#pragma unroll
            for (int j = 0; j < 4; ++j) acc[i][j] = (f32x4)0.f;

        m97_core128(Ag, NH, Bg, NH, DH, Alds, Blds, wid, lane, acc);

        int wm = wid >> 1, wn = wid & 1;
        short* dst = VWt + (size_t)b * NH * 1024 + h * 512;
#pragma unroll
        for (int i = 0; i < 4; ++i)
#pragma unroll
            for (int j = 0; j < 4; ++j) {
                int col = nt * 128 + wn * 64 + j * 16 + l15;     // s
                int row0 = mt * 128 + wm * 64 + i * 16 + crow;   // o
#pragma unroll
                for (int r = 0; r < 4; ++r)
                    dst[(size_t)(row0 + r) * 1024 + col] = f2b(acc[i][j][r]);
            }
    } else {
        // scores: S_bf[b][h][e][s] = EXP(q . K). 64 blocks (register path).
        int l = swz8(t - 256, 8); // b*8 + h*4 + st
        int b = l >> 3, h = (l >> 2) & 1, st = l & 3;
        int n0 = st * 128 + wid * 32;
        int kb = (lane >> 4) * 8;

        f32x4 acc[4][2];
#pragma unroll
        for (int i = 0; i < 4; ++i)
#pragma unroll
            for (int j = 0; j < 2; ++j) acc[i][j] = (f32x4)0.f;

        const short* Aq = q_bf + (size_t)l15 * NH + h * DH + kb;
        const short* Bk = K_bf + ((size_t)b * SL + n0 + l15) * NH + h * DH + kb;

        short8 a0[4], a1[4];
        short8 b0[2], b1[2];
        ldg4(a0, Aq, 0, NH);
        ldg2(b0, Bk, 0, NH);
#pragma unroll
        for (int p = 0; p < 4; ++p) {
            int k1 = p * 64 + 32;
            ldg4(a1, Aq, k1, NH);
            ldg2(b1, Bk, k1, NH);
            mm42(acc, a0, b0);
            if (p < 3) {
                ldg4(a0, Aq, k1 + 32, NH);
                ldg2(b0, Bk, k1 + 32, NH);
            }
            mm42(acc, a1, b1);
        }

#pragma unroll
        for (int i = 0; i < 4; ++i)
#pragma unroll
            for (int j = 0; j < 2; ++j) {
                int col = n0 + j * 16 + l15;
#pragma unroll
                for (int r = 0; r < 4; ++r) {
                    int row = i * 16 + crow + r;
                    S_bf[(((size_t)(b * HEADS + h)) * NE + row) * SL + col] = f2b(__expf(acc[i][j][r]));
                }
            }
    }
}

// ---------------------------------------------------------------------------
// pnorm: P[(b*16+ent)*64+e][h*512+s] = mask ? expS*inv : 0. grid 256.
__global__ void __launch_bounds__(256, 4)
pnorm_kernel(const short* __restrict__ S_bf,
             const void* __restrict__ ents,
             const int* __restrict__ flag,
             short* __restrict__ P) {
    int l = swz8(blockIdx.x, 32); // b*32 + ent*2 + eh
    int b = l >> 5, ent = (l >> 1) & 15, eh = l & 1;
    int tid = threadIdx.x, lane = tid & 63, wid = tid >> 6;

    unsigned att8 = 0;
    {
        size_t mbase = ((size_t)b * EN + ent) * SL + lane * 8;
        if (flag[0]) {
            const int* p = (const int*)ents;
#pragma unroll
            for (int j = 0; j < 8; ++j)
                if (p[mbase + j]) att8 |= 1u << j;
        } else {
            const unsigned char* p = (const unsigned char*)ents;
#pragma unroll
            for (int j = 0; j < 8; ++j)
                if (p[mbase + j]) att8 |= 1u << j;
        }
    }

    for (int it = 0; it < 8; ++it) {
        int e = eh * 32 + wid * 8 + it;
        const short* s0p = S_bf + (((size_t)(b * HEADS + 0)) * NE + e) * SL + lane * 8;
        const short* s1p = S_bf + (((size_t)(b * HEADS + 1)) * NE + e) * SL + lane * 8;
        short8 v0 = *(const short8*)s0p;
        short8 v1 = *(const short8*)s1p;
        float f0[8], f1[8], sum0 = 0.f, sum1 = 0.f;
#pragma unroll
        for (int j = 0; j < 8; ++j) {
            f0[j] = (att8 >> j & 1) ? b2f(v0[j]) : 0.f;
            f1[j] = (att8 >> j & 1) ? b2f(v1[j]) : 0.f;
            sum0 += f0[j];
            sum1 += f1[j];
        }
#pragma unroll
        for (int off = 32; off; off >>= 1) {
            sum0 += __shfl_xor(sum0, off);
            sum1 += __shfl_xor(sum1, off);
        }
        float iv0 = 1.f / sum0, iv1 = 1.f / sum1;
        short8 o0, o1;
#pragma unroll
        for (int j = 0; j < 8; ++j) {
            o0[j] = f2b(f0[j] * iv0);
            o1[j] = f2b(f1[j] * iv1);
        }
        short* prow = P + ((size_t)(b * EN + ent) * NE + e) * 1024;
        *(short8*)(prow + lane * 8) = o0;
        *(short8*)(prow + 512 + lane * 8) = o1;
    }
}

// ---------------------------------------------------------------------------
// outg: out = P @ VWt2^T + bo. M=8192, N=512, K=1024. 128x128 tiles, grid 256.
__global__ void __launch_bounds__(256, 2)
outg(const short* __restrict__ P,
     const short* __restrict__ VWt,
     const float* __restrict__ bo,
     float* __restrict__ out) {
    __shared__ short Alds[2 * 128 * 64];
    __shared__ short Blds[2 * 128 * 64];
    int l = swz8(blockIdx.x, 32); // b*32 + mt*4 + nt
    int b = l >> 5, mt = (l >> 2) & 7, nt = l & 3;
    int tid = threadIdx.x, lane = tid & 63, wid = tid >> 6;
    int l15 = lane & 15;
    int crow = (lane >> 4) * 4;

    const short* Ag = P + ((size_t)b * 1024 + mt * 128) * 1024;
    const short* Bg = VWt + ((size_t)b * NH + nt * 128) * 1024;

    f32x4 acc[4][4];
#pragma unroll
    for (int i = 0; i < 4; ++i)
#pragma unroll
        for (int j = 0; j < 4; ++j) acc[i][j] = (f32x4)0.f;

    m97_core128(Ag, 1024, Bg, 1024, 1024, Alds, Blds, wid, lane, acc);

    int wm = wid >> 1, wn = wid & 1;
    int gr0 = b * 1024 + mt * 128 + wm * 64;
#pragma unroll
    for (int i = 0; i < 4; ++i)
#pragma unroll
        for (int j = 0; j < 4; ++j) {
            int col = nt * 128 + wn * 64 + j * 16 + l15;
            float bval = bo[col];
#pragma unroll
            for (int r = 0; r < 4; ++r) {
                int row = gr0 + i * 16 + crow + r;
                out[(size_t)row * NH + col] = acc[i][j][r] + bval;
            }
        }
}

// ---------------------------------------------------------------------------
extern "C" void kernel_launch(void* const* d_in, const int* in_sizes, int n_in,
                              void* d_out, int out_size, void* d_ws, size_t ws_size,
                              hipStream_t stream) {
    const float* toks = (const float*)d_in[0];
    const void* ents = d_in[1];
    const float* evs = (const float*)d_in[2];
    const float* Wq = (const float*)d_in[6];
    const float* Wk = (const float*)d_in[7];
    const float* Wv = (const float*)d_in[8];
    const float* bq = (const float*)d_in[9];
    const float* bk = (const float*)d_in[10];
    const float* bv = (const float*)d_in[11];
    const float* Wo = (const float*)d_in[12];
    const float* bo = (const float*)d_in[13];

    char* ws = (char*)d_ws;
    short* toks_bf = (short*)(ws + WS_TOKS);
    short* K_bf = (short*)(ws + WS_K);
    short* V_bf = (short*)(ws + WS_V);
    short* S_bf = (short*)(ws + WS_S);
    short* Wk_bf = (short*)(ws + WS_WK);
    short* Wv_bf = (short*)(ws + WS_WV);
    short* Wo_bf = (short*)(ws + WS_WO);
    short* Wq_bf = (short*)(ws + WS_WQ);
    short* ev_bf = (short*)(ws + WS_EV);
    short* q_bf = (short*)(ws + WS_Q);
    int* flag = (int*)(ws + WS_FLAG);
    short* VWt = (short*)(ws + WS_VW);
    short* P = (short*)(ws + WS_P);

    prep_kernel<<<CH_TOTAL / 256 + 1, 256, 0, stream>>>(
        toks, Wk, Wv, Wo, Wq, evs, (const unsigned char*)ents,
        toks_bf, Wk_bf, Wv_bf, Wo_bf, Wq_bf, ev_bf, flag);
    projn<<<260, 256, 0, stream>>>(toks_bf, Wk_bf, Wv_bf, ev_bf, Wq_bf,
                                   bk, bv, bq, K_bf, V_bf, q_bf);
    vwtn_scores<<<320, 256, 0, stream>>>(V_bf, Wo_bf, q_bf, K_bf, VWt, S_bf);
    pnorm_kernel<<<256, 256, 0, stream>>>(S_bf, ents, flag, P);
    outg<<<256, 256, 0, stream>>>(P, VWt, bo, (float*)d_out);
}

// Round 23
// 51.284 us; speedup vs baseline: 2.1690x; 1.2261x over previous
//
#include <hip/hip_runtime.h>

// EntityAttention — round 23: R22 base (62.9 µs) + the two register-path
// tail branches (q-proj, scores) ported to a staged m97_core64 (M=64 tiles,
// dbuf + counted vmcnt(6)). R14 showed register-streamed loads serialize at
// ~410cy/load; these tail blocks were gating their launches.
// NB=8 SL=512 NH=512 EN=16 NE=64 HEADS=2 DH=256.

#define NB 8
#define SL 512
#define NH 512
#define EN 16
#define NE 64
#define HEADS 2
#define DH 256
#define SCALE 0.0625f

typedef __attribute__((ext_vector_type(8))) short short8;
typedef __attribute__((ext_vector_type(4))) short short4v;
typedef __attribute__((ext_vector_type(4))) float f32x4;

#define MFMA16(a, b, c) __builtin_amdgcn_mfma_f32_16x16x32_bf16(a, b, c, 0, 0, 0)

__device__ __forceinline__ short f2b(float f) {
    unsigned u = __builtin_bit_cast(unsigned, f);
    u += 0x7fffu + ((u >> 16) & 1u);
    return (short)(u >> 16);
}
__device__ __forceinline__ float b2f(short s) {
    return __builtin_bit_cast(float, ((unsigned)(unsigned short)s) << 16);
}
__device__ __forceinline__ int swz8(int hw, int chunk) {
    return (hw & 7) * chunk + (hw >> 3);
}

// async global->LDS, 16B per lane; HW writes lane l at ldsbase + l*16.
__device__ __forceinline__ void gload16(const short* g, short* l) {
    __builtin_amdgcn_global_load_lds(
        (const __attribute__((address_space(1))) unsigned int*)g,
        (__attribute__((address_space(3))) unsigned int*)l, 16, 0, 0);
}

__device__ __forceinline__ void mm42(f32x4 (&acc)[4][2], const short8 (&a)[4], const short8 (&bb)[2]) {
#pragma unroll
    for (int i = 0; i < 4; ++i)
#pragma unroll
        for (int j = 0; j < 2; ++j) acc[i][j] = MFMA16(a[i], bb[j], acc[i][j]);
}
__device__ __forceinline__ void mm44(f32x4 (&acc)[4][4], const short8 (&a)[4], const short8 (&bb)[4]) {
#pragma unroll
    for (int i = 0; i < 4; ++i)
#pragma unroll
        for (int j = 0; j < 4; ++j) acc[i][j] = MFMA16(a[i], bb[j], acc[i][j]);
}

// ---- ws byte offsets (aliasing-free layout from R19) -----------------------
#define WS_TOKS 0u
#define WS_K (4u << 20)
#define WS_V (8u << 20)
#define WS_S (20u << 20)
#define WS_WK (22u << 20)
#define WS_WV (WS_WK + (512u << 10))
#define WS_WO (WS_WV + (512u << 10))
#define WS_WQ (WS_WO + (512u << 10))
#define WS_EV (WS_WQ + (512u << 10))
#define WS_Q (WS_EV + (64u << 10))
#define WS_FLAG (WS_Q + (64u << 10))
#define WS_VW (32u << 20)  /* VWt2[b][o][h*512+s]: 32..40 MB */
#define WS_P (40u << 20)   /* P[slot][e][1024]: 40..56.8 MB */

#define CH_TOKS (NB * SL * NH / 4)
#define CH_W (NH * NH / 4)
#define CH_EV (NE * NH / 4)
#define CH_TOTAL (CH_TOKS + 4 * CH_W + CH_EV)

// ---------------------------------------------------------------------------
__global__ void prep_kernel(const float* __restrict__ toks, const float* __restrict__ Wk,
                            const float* __restrict__ Wv, const float* __restrict__ Wo,
                            const float* __restrict__ Wq, const float* __restrict__ ev,
                            const unsigned char* __restrict__ ents,
                            short* __restrict__ toks_bf, short* __restrict__ Wk_bf,
                            short* __restrict__ Wv_bf, short* __restrict__ Wo_bf,
                            short* __restrict__ Wq_bf, short* __restrict__ ev_bf,
                            int* __restrict__ flag) {
    __shared__ int red[256];
    int idx = blockIdx.x * 256 + threadIdx.x;
    if (idx < CH_TOTAL) {
        const float* src;
        short* dst;
        int off = idx;
        if (idx < CH_TOKS) { src = toks; dst = toks_bf; }
        else if (idx < CH_TOKS + CH_W) { src = Wk; dst = Wk_bf; off -= CH_TOKS; }
        else if (idx < CH_TOKS + 2 * CH_W) { src = Wv; dst = Wv_bf; off -= CH_TOKS + CH_W; }
        else if (idx < CH_TOKS + 3 * CH_W) { src = Wo; dst = Wo_bf; off -= CH_TOKS + 2 * CH_W; }
        else if (idx < CH_TOKS + 4 * CH_W) { src = Wq; dst = Wq_bf; off -= CH_TOKS + 3 * CH_W; }
        else { src = ev; dst = ev_bf; off -= CH_TOKS + 4 * CH_W; }
        f32x4 v = ((const f32x4*)src)[off];
        short4v o;
#pragma unroll
        for (int j = 0; j < 4; ++j) o[j] = f2b(v[j]);
        ((short4v*)dst)[off] = o;
    }
    if (blockIdx.x == gridDim.x - 1) {
        int tid = threadIdx.x;
        int cnt = 0;
        for (int j = 0; j < 16; ++j) {
            int off = tid * 16 + j;
            if ((off & 3) != 0 && ents[off] != 0) cnt++;
        }
        red[tid] = cnt;
        __syncthreads();
        for (int s = 128; s > 0; s >>= 1) {
            if (tid < s) red[tid] += red[tid + s];
            __syncthreads();
        }
        if (tid == 0) flag[0] = (red[0] == 0) ? 1 : 0;
    }
}

// ---------------------------------------------------------------------------
// m97 core, 128x128 tile, dbuf + counted vmcnt(8). (proven, R22)
__device__ __forceinline__ void m97_core128(
    const short* __restrict__ Ag, int lda,
    const short* __restrict__ Bg, int ldb, int K,
    short* Alds, short* Blds, int wid, int lane, f32x4 (&acc)[4][4]) {
    int wm = wid >> 1, wn = wid & 1;
    int l15 = lane & 15;
    int rl = lane >> 3;
    int xb = (lane & 7) << 4;
    int kx = (xb ^ (rl << 4)) >> 1;

    const short* aG0 = Ag + (size_t)(wid * 8 + rl) * lda + kx;
    const short* bG0 = Bg + (size_t)(wid * 8 + rl) * ldb + kx;
    size_t aCs = (size_t)32 * lda;
    size_t bCs = (size_t)32 * ldb;

    auto stage = [&](int k0, int buf) {
        short* aL0 = Alds + buf * 8192 + wid * 512;
        short* bL0 = Blds + buf * 8192 + wid * 512;
#pragma unroll
        for (int c = 0; c < 4; ++c) {
            gload16(aG0 + c * aCs + k0, aL0 + c * 2048);
            gload16(bG0 + c * bCs + k0, bL0 + c * 2048);
        }
    };
    auto compute = [&](int buf) {
        const char* Ab = (const char*)(Alds + buf * 8192);
        const char* Bb = (const char*)(Blds + buf * 8192);
#pragma unroll
        for (int kk = 0; kk < 2; ++kk) {
            int x = kk * 64 + ((lane >> 4) << 4);
            short8 af[4], bf_[4];
#pragma unroll
            for (int i = 0; i < 4; ++i) {
                int row = wm * 64 + i * 16 + l15;
                af[i] = *(const short8*)(Ab + row * 128 + (x ^ ((row & 7) << 4)));
            }
#pragma unroll
            for (int j = 0; j < 4; ++j) {
                int row = wn * 64 + j * 16 + l15;
                bf_[j] = *(const short8*)(Bb + row * 128 + (x ^ ((row & 7) << 4)));
            }
            mm44(acc, af, bf_);
        }
    };

    int nsteps = K >> 6;
    stage(0, 0);
    stage(64, 1);
    asm volatile("s_waitcnt vmcnt(8)" ::: "memory");
    __builtin_amdgcn_sched_barrier(0);
    __builtin_amdgcn_s_barrier();

    int buf = 0;
    for (int s = 0; s < nsteps; ++s, buf ^= 1) {
        compute(buf);
        if (s + 1 < nsteps) {
            __builtin_amdgcn_s_barrier();
            if (s + 2 < nsteps) {
                stage((s + 2) * 64, buf);
                asm volatile("s_waitcnt vmcnt(8)" ::: "memory");
            } else {
                asm volatile("s_waitcnt vmcnt(0)" ::: "memory");
            }
            __builtin_amdgcn_sched_barrier(0);
            __builtin_amdgcn_s_barrier();
        }
    }
}

// ---------------------------------------------------------------------------
// m97 core, 64x128 tile (A shared by all 4 waves; wave = 64 x 32 cols),
// dbuf + counted vmcnt(6). A: 64 rows (2 chunks/wave), B: 128 rows (4).
__device__ __forceinline__ void m97_core64(
    const short* __restrict__ Ag, int lda,
    const short* __restrict__ Bg, int ldb, int K,
    short* Alds, short* Blds, int wid, int lane, f32x4 (&acc)[4][2]) {
    int l15 = lane & 15;
    int rl = lane >> 3;
    int xb = (lane & 7) << 4;
    int kx = (xb ^ (rl << 4)) >> 1;

    const short* aG0 = Ag + (size_t)(wid * 8 + rl) * lda + kx;
    const short* bG0 = Bg + (size_t)(wid * 8 + rl) * ldb + kx;
    size_t aCs = (size_t)32 * lda;
    size_t bCs = (size_t)32 * ldb;

    auto stage = [&](int k0, int buf) {
        short* aL0 = Alds + buf * 4096 + wid * 512;
        short* bL0 = Blds + buf * 8192 + wid * 512;
        gload16(aG0 + k0, aL0);
        gload16(aG0 + aCs + k0, aL0 + 2048);
#pragma unroll
        for (int c = 0; c < 4; ++c)
            gload16(bG0 + c * bCs + k0, bL0 + c * 2048);
    };
    auto compute = [&](int buf) {
        const char* Ab = (const char*)(Alds + buf * 4096);
        const char* Bb = (const char*)(Blds + buf * 8192);
#pragma unroll
        for (int kk = 0; kk < 2; ++kk) {
            int x = kk * 64 + ((lane >> 4) << 4);
            short8 af[4], bf_[2];
#pragma unroll
            for (int i = 0; i < 4; ++i) {
                int row = i * 16 + l15; // 0..63
                af[i] = *(const short8*)(Ab + row * 128 + (x ^ ((row & 7) << 4)));
            }
#pragma unroll
            for (int j = 0; j < 2; ++j) {
                int row = wid * 32 + j * 16 + l15; // 0..127
                bf_[j] = *(const short8*)(Bb + row * 128 + (x ^ ((row & 7) << 4)));
            }
            mm42(acc, af, bf_);
        }
    };

    int nsteps = K >> 6; // >= 4 for all uses (K=256,512)
    stage(0, 0);
    stage(64, 1);
    asm volatile("s_waitcnt vmcnt(6)" ::: "memory");
    __builtin_amdgcn_sched_barrier(0);
    __builtin_amdgcn_s_barrier();

    int buf = 0;
    for (int s = 0; s < nsteps; ++s, buf ^= 1) {
        compute(buf);
        if (s + 1 < nsteps) {
            __builtin_amdgcn_s_barrier();
            if (s + 2 < nsteps) {
                stage((s + 2) * 64, buf);
                asm volatile("s_waitcnt vmcnt(6)" ::: "memory");
            } else {
                asm volatile("s_waitcnt vmcnt(0)" ::: "memory");
            }
            __builtin_amdgcn_sched_barrier(0);
            __builtin_amdgcn_s_barrier();
        }
    }
}

// ---------------------------------------------------------------------------
// projn: t<256: K/V projection (128x128 tiles); t>=256 (4 blocks): q staged
// (64x128 tiles, K=512).
__global__ void __launch_bounds__(256, 2)
projn(const short* __restrict__ toks_bf,
      const short* __restrict__ Wk_bf,
      const short* __restrict__ Wv_bf,
      const short* __restrict__ ev_bf,
      const short* __restrict__ Wq_bf,
      const float* __restrict__ bk, const float* __restrict__ bv,
      const float* __restrict__ bq,
      short* __restrict__ K_bf, short* __restrict__ V_bf,
      short* __restrict__ q_bf) {
    __shared__ short Alds[2 * 128 * 64];
    __shared__ short Blds[2 * 128 * 64];
    int t = blockIdx.x;
    int tid = threadIdx.x, lane = tid & 63, wid = tid >> 6;
    int l15 = lane & 15;
    int crow = (lane >> 4) * 4;

    if (t < 256) {
        int l = swz8(t, 32); // b*32 + kind*16 + mt*4 + nt
        int b = l >> 5, kind = (l >> 4) & 1, mt = (l >> 2) & 3, nt = l & 3;
        const short* Ag = toks_bf + (size_t)(b * SL + mt * 128) * NH;
        const short* Bg = (kind ? Wv_bf : Wk_bf) + (size_t)(nt * 128) * NH;
        const float* bias = kind ? bv : bk;
        short* dst = kind ? V_bf : K_bf;

        f32x4 acc[4][4];
#pragma unroll
        for (int i = 0; i < 4; ++i)
#pragma unroll
            for (int j = 0; j < 4; ++j) acc[i][j] = (f32x4)0.f;

        m97_core128(Ag, NH, Bg, NH, NH, Alds, Blds, wid, lane, acc);

        int wm = wid >> 1, wn = wid & 1;
#pragma unroll
        for (int i = 0; i < 4; ++i)
#pragma unroll
            for (int j = 0; j < 4; ++j) {
                int col = nt * 128 + wn * 64 + j * 16 + l15;
                float bval = bias[col];
                int row0 = b * SL + mt * 128 + wm * 64 + i * 16 + crow;
#pragma unroll
                for (int r = 0; r < 4; ++r)
                    dst[(size_t)(row0 + r) * NH + col] = f2b(acc[i][j][r] + bval);
            }
    } else {
        // q staged: M=64 events, N = 128 cols per block (4 blocks), K=512.
        int tq = t - 256; // 0..3
        const short* Ag = ev_bf;
        const short* Bg = Wq_bf + (size_t)(tq * 128) * NH;

        f32x4 acc[4][2];
#pragma unroll
        for (int i = 0; i < 4; ++i)
#pragma unroll
            for (int j = 0; j < 2; ++j) acc[i][j] = (f32x4)0.f;

        m97_core64(Ag, NH, Bg, NH, NH, Alds, Blds, wid, lane, acc);

#pragma unroll
        for (int i = 0; i < 4; ++i)
#pragma unroll
            for (int j = 0; j < 2; ++j) {
                int col = tq * 128 + wid * 32 + j * 16 + l15;
                float bval = bq[col];
#pragma unroll
                for (int r = 0; r < 4; ++r) {
                    int row = i * 16 + crow + r;
                    q_bf[(size_t)row * NH + col] = f2b((acc[i][j][r] + bval) * SCALE);
                }
            }
    }
}

// ---------------------------------------------------------------------------
// vwtn_scores: t<256: VWt2 tiles (128x128). t>=256 (64 blocks): scores staged
// (64x128 tiles, K=DH=256), epilogue applies expf.
__global__ void __launch_bounds__(256, 2)
vwtn_scores(const short* __restrict__ V_bf,
            const short* __restrict__ Wo_bf,
            const short* __restrict__ q_bf,
            const short* __restrict__ K_bf,
            short* __restrict__ VWt,
            short* __restrict__ S_bf) {
    __shared__ short Alds[2 * 128 * 64];
    __shared__ short Blds[2 * 128 * 64];
    int t = blockIdx.x;
    int tid = threadIdx.x, lane = tid & 63, wid = tid >> 6;
    int l15 = lane & 15;
    int crow = (lane >> 4) * 4;

    if (t < 256) {
        int l = swz8(t, 32); // bh*16 + mt*4 + nt
        int bh = l >> 4, mt = (l >> 2) & 3, nt = l & 3;
        int b = bh >> 1, h = bh & 1;

        const short* Ag = Wo_bf + (size_t)(mt * 128) * NH + h * DH;
        const short* Bg = V_bf + (size_t)(b * SL + nt * 128) * NH + h * DH;

        f32x4 acc[4][4];
#pragma unroll
        for (int i = 0; i < 4; ++i)
#pragma unroll
            for (int j = 0; j < 4; ++j) acc[i][j] = (f32x4)0.f;

        m97_core128(Ag, NH, Bg, NH, DH, Alds, Blds, wid, lane, acc);

        int wm = wid >> 1, wn = wid & 1;
        short* dst = VWt + (size_t)b * NH * 1024 + h * 512;
#pragma unroll
        for (int i = 0; i < 4; ++i)
#pragma unroll
            for (int j = 0; j < 4; ++j) {
                int col = nt * 128 + wn * 64 + j * 16 + l15;     // s
                int row0 = mt * 128 + wm * 64 + i * 16 + crow;   // o
#pragma unroll
                for (int r = 0; r < 4; ++r)
                    dst[(size_t)(row0 + r) * 1024 + col] = f2b(acc[i][j][r]);
            }
    } else {
        // scores staged: S_bf[b][h][e][s] = EXP(q . K). 64 blocks, 64x128.
        int l = swz8(t - 256, 8); // b*8 + h*4 + st
        int b = l >> 3, h = (l >> 2) & 1, st = l & 3;

        const short* Ag = q_bf + h * DH;                                 // 64 x 256
        const short* Bg = K_bf + (size_t)(b * SL + st * 128) * NH + h * DH; // 128 x 256

        f32x4 acc[4][2];
#pragma unroll
        for (int i = 0; i < 4; ++i)
#pragma unroll
            for (int j = 0; j < 2; ++j) acc[i][j] = (f32x4)0.f;

        m97_core64(Ag, NH, Bg, NH, DH, Alds, Blds, wid, lane, acc);

#pragma unroll
        for (int i = 0; i < 4; ++i)
#pragma unroll
            for (int j = 0; j < 2; ++j) {
                int col = st * 128 + wid * 32 + j * 16 + l15;
#pragma unroll
                for (int r = 0; r < 4; ++r) {
                    int row = i * 16 + crow + r;
                    S_bf[(((size_t)(b * HEADS + h)) * NE + row) * SL + col] = f2b(__expf(acc[i][j][r]));
                }
            }
    }
}

// ---------------------------------------------------------------------------
// pnorm: P[(b*16+ent)*64+e][h*512+s] = mask ? expS*inv : 0. grid 256.
__global__ void __launch_bounds__(256, 4)
pnorm_kernel(const short* __restrict__ S_bf,
             const void* __restrict__ ents,
             const int* __restrict__ flag,
             short* __restrict__ P) {
    int l = swz8(blockIdx.x, 32); // b*32 + ent*2 + eh
    int b = l >> 5, ent = (l >> 1) & 15, eh = l & 1;
    int tid = threadIdx.x, lane = tid & 63, wid = tid >> 6;

    unsigned att8 = 0;
    {
        size_t mbase = ((size_t)b * EN + ent) * SL + lane * 8;
        if (flag[0]) {
            const int* p = (const int*)ents;
#pragma unroll
            for (int j = 0; j < 8; ++j)
                if (p[mbase + j]) att8 |= 1u << j;
        } else {
            const unsigned char* p = (const unsigned char*)ents;
#pragma unroll
            for (int j = 0; j < 8; ++j)
                if (p[mbase + j]) att8 |= 1u << j;
        }
    }

    for (int it = 0; it < 8; ++it) {
        int e = eh * 32 + wid * 8 + it;
        const short* s0p = S_bf + (((size_t)(b * HEADS + 0)) * NE + e) * SL + lane * 8;
        const short* s1p = S_bf + (((size_t)(b * HEADS + 1)) * NE + e) * SL + lane * 8;
        short8 v0 = *(const short8*)s0p;
        short8 v1 = *(const short8*)s1p;
        float f0[8], f1[8], sum0 = 0.f, sum1 = 0.f;
#pragma unroll
        for (int j = 0; j < 8; ++j) {
            f0[j] = (att8 >> j & 1) ? b2f(v0[j]) : 0.f;
            f1[j] = (att8 >> j & 1) ? b2f(v1[j]) : 0.f;
            sum0 += f0[j];
            sum1 += f1[j];
        }
#pragma unroll
        for (int off = 32; off; off >>= 1) {
            sum0 += __shfl_xor(sum0, off);
            sum1 += __shfl_xor(sum1, off);
        }
        float iv0 = 1.f / sum0, iv1 = 1.f / sum1;
        short8 o0, o1;
#pragma unroll
        for (int j = 0; j < 8; ++j) {
            o0[j] = f2b(f0[j] * iv0);
            o1[j] = f2b(f1[j] * iv1);
        }
        short* prow = P + ((size_t)(b * EN + ent) * NE + e) * 1024;
        *(short8*)(prow + lane * 8) = o0;
        *(short8*)(prow + 512 + lane * 8) = o1;
    }
}

// ---------------------------------------------------------------------------
// outg: out = P @ VWt2^T + bo. M=8192, N=512, K=1024. 128x128 tiles, grid 256.
__global__ void __launch_bounds__(256, 2)
outg(const short* __restrict__ P,
     const short* __restrict__ VWt,
     const float* __restrict__ bo,
     float* __restrict__ out) {
    __shared__ short Alds[2 * 128 * 64];
    __shared__ short Blds[2 * 128 * 64];
    int l = swz8(blockIdx.x, 32); // b*32 + mt*4 + nt
    int b = l >> 5, mt = (l >> 2) & 7, nt = l & 3;
    int tid = threadIdx.x, lane = tid & 63, wid = tid >> 6;
    int l15 = lane & 15;
    int crow = (lane >> 4) * 4;

    const short* Ag = P + ((size_t)b * 1024 + mt * 128) * 1024;
    const short* Bg = VWt + ((size_t)b * NH + nt * 128) * 1024;

    f32x4 acc[4][4];
#pragma unroll
    for (int i = 0; i < 4; ++i)
#pragma unroll
        for (int j = 0; j < 4; ++j) acc[i][j] = (f32x4)0.f;

    m97_core128(Ag, 1024, Bg, 1024, 1024, Alds, Blds, wid, lane, acc);

    int wm = wid >> 1, wn = wid & 1;
    int gr0 = b * 1024 + mt * 128 + wm * 64;
#pragma unroll
    for (int i = 0; i < 4; ++i)
#pragma unroll
        for (int j = 0; j < 4; ++j) {
            int col = nt * 128 + wn * 64 + j * 16 + l15;
            float bval = bo[col];
#pragma unroll
            for (int r = 0; r < 4; ++r) {
                int row = gr0 + i * 16 + crow + r;
                out[(size_t)row * NH + col] = acc[i][j][r] + bval;
            }
        }
}

// ---------------------------------------------------------------------------
extern "C" void kernel_launch(void* const* d_in, const int* in_sizes, int n_in,
                              void* d_out, int out_size, void* d_ws, size_t ws_size,
                              hipStream_t stream) {
    const float* toks = (const float*)d_in[0];
    const void* ents = d_in[1];
    const float* evs = (const float*)d_in[2];
    const float* Wq = (const float*)d_in[6];
    const float* Wk = (const float*)d_in[7];
    const float* Wv = (const float*)d_in[8];
    const float* bq = (const float*)d_in[9];
    const float* bk = (const float*)d_in[10];
    const float* bv = (const float*)d_in[11];
    const float* Wo = (const float*)d_in[12];
    const float* bo = (const float*)d_in[13];

    char* ws = (char*)d_ws;
    short* toks_bf = (short*)(ws + WS_TOKS);
    short* K_bf = (short*)(ws + WS_K);
    short* V_bf = (short*)(ws + WS_V);
    short* S_bf = (short*)(ws + WS_S);
    short* Wk_bf = (short*)(ws + WS_WK);
    short* Wv_bf = (short*)(ws + WS_WV);
    short* Wo_bf = (short*)(ws + WS_WO);
    short* Wq_bf = (short*)(ws + WS_WQ);
    short* ev_bf = (short*)(ws + WS_EV);
    short* q_bf = (short*)(ws + WS_Q);
    int* flag = (int*)(ws + WS_FLAG);
    short* VWt = (short*)(ws + WS_VW);
    short* P = (short*)(ws + WS_P);

    prep_kernel<<<CH_TOTAL / 256 + 1, 256, 0, stream>>>(
        toks, Wk, Wv, Wo, Wq, evs, (const unsigned char*)ents,
        toks_bf, Wk_bf, Wv_bf, Wo_bf, Wq_bf, ev_bf, flag);
    projn<<<260, 256, 0, stream>>>(toks_bf, Wk_bf, Wv_bf, ev_bf, Wq_bf,
                                   bk, bv, bq, K_bf, V_bf, q_bf);
    vwtn_scores<<<320, 256, 0, stream>>>(V_bf, Wo_bf, q_bf, K_bf, VWt, S_bf);
    pnorm_kernel<<<256, 256, 0, stream>>>(S_bf, ents, flag, P);
    outg<<<256, 256, 0, stream>>>(P, VWt, bo, (float*)d_out);
}